// Round 2
// baseline (690.008 us; speedup 1.0000x reference)
//
#include <hip/hip_runtime.h>
#include <hip/hip_bf16.h>

// GConvGRU (ChebConv K=2), fp32 in/out, bf16 MFMA internally:
//  1) degree count (atomics) -> 2) scan+norm (1 block) -> 3) CSR fill
//  4) weight prepack fp32->bf16 (transposed, zero-padded blocks) + fp32 bias pack
//  5) convert x,hx -> bf16 (compact arrays + Zin x/hx slots)
//  6) wave-per-node gather-aggregate -> px,ph slots of Zin = [x|px|hx|ph] (K=512)
//  7) MFMA bf16 GEMM  Z[M,512] = Zin[M,512] @ Wcat^T (Wcat stored [col][k])
//  8) gate epilogue -> hy (fp32)

typedef unsigned short u16;
typedef unsigned int u32;
typedef __attribute__((ext_vector_type(8))) __bf16 bf16x8;
typedef __attribute__((ext_vector_type(4))) float f32x4;

#define F_IN 128
#define HID 128

__device__ __forceinline__ u16 f2bf(float f) {
    u32 u;
    __builtin_memcpy(&u, &f, 4);
    u = (u + 0x7fffu + ((u >> 16) & 1u)) >> 16;
    return (u16)u;
}
__device__ __forceinline__ float bf2f(u16 b) {
    u32 u = ((u32)b) << 16;
    float f;
    __builtin_memcpy(&f, &u, 4);
    return f;
}
__device__ __forceinline__ float sigmoidf_(float x) {
    return 1.0f / (1.0f + __expf(-x));
}

// async 16B global -> LDS (lds base wave-uniform; HW adds lane*16)
__device__ __forceinline__ void async_copy16(void* lds, const void* gptr) {
    __builtin_amdgcn_global_load_lds(
        (__attribute__((address_space(1))) void*)gptr,
        (__attribute__((address_space(3))) void*)lds,
        16, 0, 0);
}

// ---------------- 1. degree count ----------------
__global__ void count_kernel(const int* __restrict__ dst, int E, int* __restrict__ counts) {
    int i = blockIdx.x * blockDim.x + threadIdx.x;
    if (i < E) atomicAdd(&counts[dst[i]], 1);
}

// ---------------- 2. exclusive scan + cursor + norm ----------------
__global__ void scan_kernel(const int* __restrict__ counts, int* __restrict__ row_ptr,
                            int* __restrict__ cursor, float* __restrict__ norm, int N) {
    const int T = 1024;
    int tid = threadIdx.x;
    int per = (N + T - 1) / T;
    int beg = tid * per;
    int end = beg + per; if (end > N) end = N;
    if (beg > N) beg = N;
    int sum = 0;
    for (int i = beg; i < end; ++i) sum += counts[i];
    __shared__ int buf[1024];
    buf[tid] = sum;
    __syncthreads();
    for (int off = 1; off < T; off <<= 1) {
        int t = (tid >= off) ? buf[tid - off] : 0;
        __syncthreads();
        buf[tid] += t;
        __syncthreads();
    }
    int run = buf[tid] - sum;  // exclusive prefix of this thread's range
    for (int i = beg; i < end; ++i) {
        int v = counts[i];
        row_ptr[i] = run;
        cursor[i] = run;
        norm[i] = rsqrtf((float)(v > 1 ? v : 1));
        run += v;
    }
    if (tid == T - 1) row_ptr[N] = run;
}

// ---------------- 3. CSR fill ----------------
__global__ void fill_kernel(const int* __restrict__ src, const int* __restrict__ dst, int E,
                            int* __restrict__ cursor, int* __restrict__ esrc) {
    int i = blockIdx.x * blockDim.x + threadIdx.x;
    if (i < E) {
        int d = dst[i];
        int slot = atomicAdd(&cursor[d], 1);
        esrc[slot] = src[i];
    }
}

// ---------------- 4. weight prepack (fp32 -> bf16) ----------------
// WT[c][k]: c in [0,512) output col (r|u|cx|ch), k in [0,512) concat (x|px|hx|ph)
__global__ void prep_kernel(const float* __restrict__ Wrx, const float* __restrict__ Wrh,
                            const float* __restrict__ Wux, const float* __restrict__ Wuh,
                            const float* __restrict__ Wcx, const float* __restrict__ Wch,
                            const float* __restrict__ brx, const float* __restrict__ brh,
                            const float* __restrict__ bux, const float* __restrict__ buh,
                            const float* __restrict__ bcx, const float* __restrict__ bch,
                            u16* __restrict__ WT, float* __restrict__ bias) {
    int t = blockIdx.x * blockDim.x + threadIdx.x;  // 0 .. 512*512-1
    int c = t >> 9, k = t & 511;
    int part = c >> 7, c0 = c & 127;
    int kpart = k >> 7, kf = k & 127;
    float val = 0.0f;
    if (part == 0) {
        const float* W = (kpart < 2) ? Wrx : Wrh;
        val = W[(kpart & 1) * (128 * 128) + kf * 128 + c0];
    } else if (part == 1) {
        const float* W = (kpart < 2) ? Wux : Wuh;
        val = W[(kpart & 1) * (128 * 128) + kf * 128 + c0];
    } else if (part == 2) {
        if (kpart < 2) val = Wcx[(kpart & 1) * (128 * 128) + kf * 128 + c0];
    } else {
        if (kpart >= 2) val = Wch[(kpart & 1) * (128 * 128) + kf * 128 + c0];
    }
    WT[c * 512 + k] = f2bf(val);
    if (t < 512) {
        int bp = t >> 7, bc = t & 127;
        float b = 0.0f;
        if (bp == 0) b = brx[bc] + brh[bc];
        else if (bp == 1) b = bux[bc] + buh[bc];
        else if (bp == 2) b = bcx[bc];
        else b = bch[bc];
        bias[t] = b;
    }
}

// ---------------- 5. fp32 -> bf16 convert (compact + Zin slots) ----------------
// one thread = 2 consecutive features of one node (packs a u32)
__global__ void convert_kernel(const float* __restrict__ x, const float* __restrict__ hx,
                               u32* __restrict__ xb, u32* __restrict__ hb,
                               u32* __restrict__ zin, int N) {
    int t = blockIdx.x * blockDim.x + threadIdx.x;  // [0, N*64)
    if (t >= N * 64) return;
    int n = t >> 6, l = t & 63;
    float2 vx = ((const float2*)x)[t];
    float2 vh = ((const float2*)hx)[t];
    u32 px = (((u32)f2bf(vx.y)) << 16) | (u32)f2bf(vx.x);
    u32 ph = (((u32)f2bf(vh.y)) << 16) | (u32)f2bf(vh.x);
    xb[t] = px;
    hb[t] = ph;
    zin[(size_t)n * 256 + l] = px;          // x slot
    zin[(size_t)n * 256 + 128 + l] = ph;    // hx slot
}

// ---------------- 6. wave-per-node gather-aggregate ----------------
__global__ __launch_bounds__(256) void agg_kernel(const int* __restrict__ row_ptr,
                                                  const int* __restrict__ esrc,
                                                  const float* __restrict__ norm,
                                                  const u32* __restrict__ xb,
                                                  const u32* __restrict__ hb,
                                                  u32* __restrict__ zin, int N) {
    int node = blockIdx.x * 4 + (threadIdx.x >> 6);
    int lane = threadIdx.x & 63;
    if (node >= N) return;
    int beg = row_ptr[node], end = row_ptr[node + 1];
    float ax0 = 0.f, ax1 = 0.f, ah0 = 0.f, ah1 = 0.f;
    for (int e = beg; e < end; ++e) {
        int s = esrc[e];
        float ns = norm[s];
        u32 vx = xb[(size_t)s * 64 + lane];
        u32 vh = hb[(size_t)s * 64 + lane];
        ax0 += bf2f((u16)(vx & 0xffffu)) * ns;
        ax1 += bf2f((u16)(vx >> 16)) * ns;
        ah0 += bf2f((u16)(vh & 0xffffu)) * ns;
        ah1 += bf2f((u16)(vh >> 16)) * ns;
    }
    float nn = norm[node];
    u32* z = zin + (size_t)node * 256;
    z[64 + lane]  = (((u32)f2bf(-ax1 * nn)) << 16) | (u32)f2bf(-ax0 * nn);   // px
    z[192 + lane] = (((u32)f2bf(-ah1 * nn)) << 16) | (u32)f2bf(-ah0 * nn);   // ph
}

// ---------------- 7. MFMA GEMM: Z[M,512] = A[M,512] * B^T (B stored [n][k]) ----------------
__global__ __launch_bounds__(256) void gemm_kernel(const u16* __restrict__ A,
                                                   const u16* __restrict__ B,
                                                   u16* __restrict__ C, int M) {
    __shared__ __align__(16) __bf16 As[128 * 32];
    __shared__ __align__(16) __bf16 Bs[128 * 32];
    int tid = threadIdx.x;
    int wave = tid >> 6, lane = tid & 63;
    int m0 = blockIdx.x * 128;
    int n0 = blockIdx.y * 128;
    int wm = wave & 1, wn = wave >> 1;
    int quad = lane >> 4, l15 = lane & 15;

    f32x4 acc[4][4];
#pragma unroll
    for (int mi = 0; mi < 4; ++mi)
#pragma unroll
        for (int ni = 0; ni < 4; ++ni) acc[mi][ni] = (f32x4){0.f, 0.f, 0.f, 0.f};

    for (int k0 = 0; k0 < 512; k0 += 32) {
        __syncthreads();  // previous compute done before overwrite
#pragma unroll
        for (int j = 0; j < 2; ++j) {
            int chunk = wave * 2 + j;            // 0..7, 1KB each
            int fl = chunk * 512 + lane * 8;     // flat bf16 idx in [128][32] tile
            int row = fl >> 5;
            int col = fl & 31;
            async_copy16(&As[chunk * 512], A + (size_t)(m0 + row) * 512 + k0 + col);
            async_copy16(&Bs[chunk * 512], B + (size_t)(n0 + row) * 512 + k0 + col);
        }
        __syncthreads();  // drains vmcnt before barrier
        bf16x8 af[4], bfr[4];
#pragma unroll
        for (int mi = 0; mi < 4; ++mi)
            af[mi] = *(const bf16x8*)&As[(wm * 64 + mi * 16 + l15) * 32 + quad * 8];
#pragma unroll
        for (int ni = 0; ni < 4; ++ni)
            bfr[ni] = *(const bf16x8*)&Bs[(wn * 64 + ni * 16 + l15) * 32 + quad * 8];
#pragma unroll
        for (int mi = 0; mi < 4; ++mi)
#pragma unroll
            for (int ni = 0; ni < 4; ++ni)
                acc[mi][ni] = __builtin_amdgcn_mfma_f32_16x16x32_bf16(af[mi], bfr[ni],
                                                                      acc[mi][ni], 0, 0, 0);
    }
    // C/D layout: col = lane&15, row = quad*4 + reg
#pragma unroll
    for (int mi = 0; mi < 4; ++mi)
#pragma unroll
        for (int ni = 0; ni < 4; ++ni)
#pragma unroll
            for (int r = 0; r < 4; ++r) {
                int row = m0 + wm * 64 + mi * 16 + quad * 4 + r;
                int col = n0 + wn * 64 + ni * 16 + l15;
                C[(size_t)row * 512 + col] = f2bf(acc[mi][ni][r]);
            }
}

// ---------------- 8. gate epilogue (fp32 out) ----------------
__global__ void epilogue_kernel(const u16* __restrict__ Z, const float* __restrict__ bias,
                                const float* __restrict__ hx, float* __restrict__ out, int N) {
    int t = blockIdx.x * blockDim.x + threadIdx.x;
    if (t >= N * 128) return;
    int n = t >> 7, f = t & 127;
    const u16* z = Z + (size_t)n * 512;
    float zr = bf2f(z[f]) + bias[f];
    float zu = bf2f(z[128 + f]) + bias[128 + f];
    float zcx = bf2f(z[256 + f]) + bias[256 + f];
    float zch = bf2f(z[384 + f]) + bias[384 + f];
    float r = sigmoidf_(zr);
    float u = sigmoidf_(zu);
    float c = sigmoidf_(zcx + zch * r);
    float h = hx[t];
    float hy = u * h + (1.0f - u) * c;
    out[t] = hy;
}

extern "C" void kernel_launch(void* const* d_in, const int* in_sizes, int n_in,
                              void* d_out, int out_size, void* d_ws, size_t ws_size,
                              hipStream_t stream) {
    const int* ei = (const int*)d_in[0];
    int E = in_sizes[0] / 2;
    const float* x = (const float*)d_in[1];
    const float* hx = (const float*)d_in[2];
    int N = in_sizes[1] / F_IN;
    const float* Wrx = (const float*)d_in[3];
    const float* brx = (const float*)d_in[4];
    const float* Wrh = (const float*)d_in[5];
    const float* brh = (const float*)d_in[6];
    const float* Wux = (const float*)d_in[7];
    const float* bux = (const float*)d_in[8];
    const float* Wuh = (const float*)d_in[9];
    const float* buh = (const float*)d_in[10];
    const float* Wcx = (const float*)d_in[11];
    const float* bcx = (const float*)d_in[12];
    const float* Wch = (const float*)d_in[13];
    const float* bch = (const float*)d_in[14];

    int Mpad = ((N + 127) / 128) * 128;

    char* ws = (char*)d_ws;
    size_t off = 0;
    auto alloc = [&](size_t bytes) {
        size_t o = off;
        off = (off + bytes + 255) & ~(size_t)255;
        return o;
    };
    int* counts = (int*)(ws + alloc((size_t)N * 4));
    int* cursor = (int*)(ws + alloc((size_t)N * 4));
    int* row_ptr = (int*)(ws + alloc((size_t)(N + 1) * 4));
    float* norm = (float*)(ws + alloc((size_t)N * 4));
    int* esrc = (int*)(ws + alloc((size_t)E * 4));
    u16* WT = (u16*)(ws + alloc((size_t)512 * 512 * 2));
    float* bias = (float*)(ws + alloc((size_t)512 * 4));
    u32* xb = (u32*)(ws + alloc((size_t)N * 64 * 4));
    u32* hb = (u32*)(ws + alloc((size_t)N * 64 * 4));
    u16* Zin = (u16*)(ws + alloc((size_t)Mpad * 512 * 2));
    u16* Zout = (u16*)(ws + alloc((size_t)Mpad * 512 * 2));
    (void)ws_size;

    hipMemsetAsync(counts, 0, (size_t)N * 4, stream);
    count_kernel<<<(E + 255) / 256, 256, 0, stream>>>(ei + E, E, counts);
    scan_kernel<<<1, 1024, 0, stream>>>(counts, row_ptr, cursor, norm, N);
    fill_kernel<<<(E + 255) / 256, 256, 0, stream>>>(ei, ei + E, E, cursor, esrc);
    prep_kernel<<<1024, 256, 0, stream>>>(Wrx, Wrh, Wux, Wuh, Wcx, Wch,
                                          brx, brh, bux, buh, bcx, bch, WT, bias);
    convert_kernel<<<(N * 64 + 255) / 256, 256, 0, stream>>>(x, hx, xb, hb, (u32*)Zin, N);
    agg_kernel<<<(N + 3) / 4, 256, 0, stream>>>(row_ptr, esrc, norm, xb, hb, (u32*)Zin, N);
    dim3 ggrid(Mpad / 128, 4);
    gemm_kernel<<<ggrid, 256, 0, stream>>>(Zin, WT, Zout, Mpad);
    epilogue_kernel<<<((size_t)N * 128 + 255) / 256, 256, 0, stream>>>(Zout, bias, hx,
                                                                       (float*)d_out, N);
}

// Round 3
// 613.492 us; speedup vs baseline: 1.1247x; 1.1247x over previous
//
#include <hip/hip_runtime.h>
#include <hip/hip_bf16.h>

// GConvGRU (ChebConv K=2), fp32 in/out, bf16 MFMA internally.
// K-layout of Zin rows: [x | hx | px | ph] (512 bf16 = 1 KB per node) so the
// gather source (x|hx) is one contiguous 512 B block per node.
// Pipeline: memset -> setup(count+convert+prep) -> scan -> fill -> agg -> gemm -> epilogue

typedef unsigned short u16;
typedef unsigned int u32;
typedef __attribute__((ext_vector_type(8))) __bf16 bf16x8;
typedef __attribute__((ext_vector_type(4))) float f32x4;

#define F_IN 128
#define HID 128

__device__ __forceinline__ u16 f2bf(float f) {
    u32 u;
    __builtin_memcpy(&u, &f, 4);
    u = (u + 0x7fffu + ((u >> 16) & 1u)) >> 16;
    return (u16)u;
}
__device__ __forceinline__ float bf2f(u16 b) {
    u32 u = ((u32)b) << 16;
    float f;
    __builtin_memcpy(&f, &u, 4);
    return f;
}
__device__ __forceinline__ float bflo(u32 w) {  // low bf16 of packed pair
    u32 u = w << 16;
    float f;
    __builtin_memcpy(&f, &u, 4);
    return f;
}
__device__ __forceinline__ float bfhi(u32 w) {  // high bf16 of packed pair
    u32 u = w & 0xffff0000u;
    float f;
    __builtin_memcpy(&f, &u, 4);
    return f;
}
__device__ __forceinline__ u32 packbf(float a, float b) {
    return ((u32)f2bf(b) << 16) | (u32)f2bf(a);
}
__device__ __forceinline__ float sigmoidf_(float x) {
    return 1.0f / (1.0f + __expf(-x));
}

__device__ __forceinline__ void async_copy16(void* lds, const void* gptr) {
    __builtin_amdgcn_global_load_lds(
        (__attribute__((address_space(1))) void*)gptr,
        (__attribute__((address_space(3))) void*)lds,
        16, 0, 0);
}

// ------------- 1. fused setup: degree count | x,hx->bf16 into Zin | weight prepack -------------
__global__ void setup_kernel(const int* __restrict__ dst, int E, int* __restrict__ counts,
                             const float* __restrict__ x, const float* __restrict__ hx,
                             u32* __restrict__ zin, int N,
                             const float* __restrict__ Wrx, const float* __restrict__ Wrh,
                             const float* __restrict__ Wux, const float* __restrict__ Wuh,
                             const float* __restrict__ Wcx, const float* __restrict__ Wch,
                             const float* __restrict__ brx, const float* __restrict__ brh,
                             const float* __restrict__ bux, const float* __restrict__ buh,
                             const float* __restrict__ bcx, const float* __restrict__ bch,
                             u16* __restrict__ WT, float* __restrict__ bias,
                             int BC, int BV) {
    int bid = blockIdx.x;
    if (bid < BC) {
        int i = bid * 256 + threadIdx.x;
        if (i < E) atomicAdd(&counts[dst[i]], 1);
    } else if (bid < BC + BV) {
        int t = (bid - BC) * 256 + threadIdx.x;  // [0, N*64)
        if (t < N * 64) {
            int n = t >> 6, l = t & 63;
            float2 vx = ((const float2*)x)[t];
            float2 vh = ((const float2*)hx)[t];
            zin[(size_t)n * 256 + l] = packbf(vx.x, vx.y);        // x slot [0,64)
            zin[(size_t)n * 256 + 64 + l] = packbf(vh.x, vh.y);   // hx slot [64,128)
        }
    } else {
        int t = (bid - BC - BV) * 256 + threadIdx.x;  // [0, 512*512)
        int c = t >> 9, k = t & 511;
        int part = c >> 7, c0 = c & 127;
        int kpart = k >> 9 ? 0 : (k >> 7);  // k < 512 always; kpart = k>>7
        kpart = k >> 7;
        int kf = k & 127;
        int t01 = (kpart & 2) ? 1 : 0;     // x,hx -> T0 weight; px,ph -> T1 weight
        bool isX = !(kpart & 1);           // kpart 0,2 = x-side; 1,3 = h-side
        int wi = t01 * (128 * 128) + kf * 128 + c0;
        float val = 0.0f;
        if (part == 0) val = isX ? Wrx[wi] : Wrh[wi];
        else if (part == 1) val = isX ? Wux[wi] : Wuh[wi];
        else if (part == 2) { if (isX) val = Wcx[wi]; }
        else { if (!isX) val = Wch[wi]; }
        WT[c * 512 + k] = f2bf(val);
        if (t < 512) {
            int bp = t >> 7, bc = t & 127;
            float b = 0.0f;
            if (bp == 0) b = brx[bc] + brh[bc];
            else if (bp == 1) b = bux[bc] + buh[bc];
            else if (bp == 2) b = bcx[bc];
            else b = bch[bc];
            bias[t] = b;
        }
    }
}

// ------------- 2. exclusive scan + cursor + norm -------------
__global__ void scan_kernel(const int* __restrict__ counts, int* __restrict__ row_ptr,
                            int* __restrict__ cursor, float* __restrict__ norm, int N) {
    const int T = 1024;
    int tid = threadIdx.x;
    int per = (N + T - 1) / T;
    int beg = tid * per;
    int end = beg + per;
    if (end > N) end = N;
    if (beg > N) beg = N;
    int sum = 0;
    for (int i = beg; i < end; ++i) sum += counts[i];
    __shared__ int buf[1024];
    buf[tid] = sum;
    __syncthreads();
    for (int off = 1; off < T; off <<= 1) {
        int t = (tid >= off) ? buf[tid - off] : 0;
        __syncthreads();
        buf[tid] += t;
        __syncthreads();
    }
    int run = buf[tid] - sum;
    for (int i = beg; i < end; ++i) {
        int v = counts[i];
        row_ptr[i] = run;
        cursor[i] = run;
        norm[i] = rsqrtf((float)(v > 1 ? v : 1));
        run += v;
    }
    if (tid == T - 1) row_ptr[N] = run;
}

// ------------- 3. CSR fill -------------
__global__ void fill_kernel(const int* __restrict__ src, const int* __restrict__ dst, int E,
                            int* __restrict__ cursor, int* __restrict__ esrc) {
    int i = blockIdx.x * blockDim.x + threadIdx.x;
    if (i < E) {
        int d = dst[i];
        int slot = atomicAdd(&cursor[d], 1);
        esrc[slot] = src[i];
    }
}

// ------------- 4. wave-per-node gather-aggregate -------------
// Half-wave (32 lanes x 16 B) covers one node's contiguous x|hx 512 B block.
// 2 edges per iteration; (esrc,norm) of next chunk prefetched.
__global__ __launch_bounds__(256) void agg_kernel(const int* __restrict__ row_ptr,
                                                  const int* __restrict__ esrc,
                                                  const float* __restrict__ norm,
                                                  u32* __restrict__ zin, int N) {
    int node = blockIdx.x * 4 + (threadIdx.x >> 6);
    int lane = threadIdx.x & 63;
    if (node >= N) return;
    int h = lane >> 5;     // which edge of the pair
    int li = lane & 31;    // 16 B slot within the 512 B x|hx block
    int beg = row_ptr[node], end = row_ptr[node + 1];
    const uint4* z4 = (const uint4*)zin;  // 64 uint4 per node row
    float a0 = 0.f, a1 = 0.f, a2 = 0.f, a3 = 0.f, a4 = 0.f, a5 = 0.f, a6 = 0.f, a7 = 0.f;
    if (beg < end) {
        int e = beg;
        int eq = e + h;
        int ec = eq < end ? eq : end - 1;
        int s = esrc[ec];
        float ns = (eq < end) ? norm[s] : 0.f;
        for (;;) {
            uint4 v = z4[(size_t)s * 64 + li];
            int e2 = e + 2;
            int s2 = s;
            float ns2 = 0.f;
            bool more = e2 < end;
            if (more) {
                int eq2 = e2 + h;
                int ec2 = eq2 < end ? eq2 : end - 1;
                s2 = esrc[ec2];
                ns2 = (eq2 < end) ? norm[s2] : 0.f;
            }
            a0 += bflo(v.x) * ns; a1 += bfhi(v.x) * ns;
            a2 += bflo(v.y) * ns; a3 += bfhi(v.y) * ns;
            a4 += bflo(v.z) * ns; a5 += bfhi(v.z) * ns;
            a6 += bflo(v.w) * ns; a7 += bfhi(v.w) * ns;
            if (!more) break;
            s = s2; ns = ns2; e = e2;
        }
    }
    // combine the two edge-halves: lanes l and l+32 hold the same 8 features
    a0 += __shfl_xor(a0, 32); a1 += __shfl_xor(a1, 32);
    a2 += __shfl_xor(a2, 32); a3 += __shfl_xor(a3, 32);
    a4 += __shfl_xor(a4, 32); a5 += __shfl_xor(a5, 32);
    a6 += __shfl_xor(a6, 32); a7 += __shfl_xor(a7, 32);
    if (lane < 32) {
        float nn = -norm[node];
        uint4 o;
        o.x = packbf(a0 * nn, a1 * nn);
        o.y = packbf(a2 * nn, a3 * nn);
        o.z = packbf(a4 * nn, a5 * nn);
        o.w = packbf(a6 * nn, a7 * nn);
        // px|ph occupy bytes [512,1024) = uint4 slots [32,64): same feature mapping
        ((uint4*)zin)[(size_t)node * 64 + 32 + li] = o;
    }
}

// ------------- 5. MFMA GEMM: Z[M,512] = A[M,512] * B^T (B stored [col][k]) -------------
__global__ __launch_bounds__(256) void gemm_kernel(const u16* __restrict__ A,
                                                   const u16* __restrict__ B,
                                                   u16* __restrict__ C, int M) {
    __shared__ __align__(16) __bf16 As[128 * 32];
    __shared__ __align__(16) __bf16 Bs[128 * 32];
    int tid = threadIdx.x;
    int wave = tid >> 6, lane = tid & 63;
    int m0 = blockIdx.x * 128;
    int n0 = blockIdx.y * 128;
    int wm = wave & 1, wn = wave >> 1;
    int quad = lane >> 4, l15 = lane & 15;

    f32x4 acc[4][4];
#pragma unroll
    for (int mi = 0; mi < 4; ++mi)
#pragma unroll
        for (int ni = 0; ni < 4; ++ni) acc[mi][ni] = (f32x4){0.f, 0.f, 0.f, 0.f};

    for (int k0 = 0; k0 < 512; k0 += 32) {
        __syncthreads();
#pragma unroll
        for (int j = 0; j < 2; ++j) {
            int chunk = wave * 2 + j;            // 0..7, 1 KB each
            int fl = chunk * 512 + lane * 8;
            int row = fl >> 5;
            int col = fl & 31;
            async_copy16(&As[chunk * 512], A + (size_t)(m0 + row) * 512 + k0 + col);
            async_copy16(&Bs[chunk * 512], B + (size_t)(n0 + row) * 512 + k0 + col);
        }
        __syncthreads();
        bf16x8 af[4], bfr[4];
#pragma unroll
        for (int mi = 0; mi < 4; ++mi)
            af[mi] = *(const bf16x8*)&As[(wm * 64 + mi * 16 + l15) * 32 + quad * 8];
#pragma unroll
        for (int ni = 0; ni < 4; ++ni)
            bfr[ni] = *(const bf16x8*)&Bs[(wn * 64 + ni * 16 + l15) * 32 + quad * 8];
#pragma unroll
        for (int mi = 0; mi < 4; ++mi)
#pragma unroll
            for (int ni = 0; ni < 4; ++ni)
                acc[mi][ni] = __builtin_amdgcn_mfma_f32_16x16x32_bf16(af[mi], bfr[ni],
                                                                      acc[mi][ni], 0, 0, 0);
    }
    // C/D layout: col = lane&15, row = quad*4 + reg
#pragma unroll
    for (int mi = 0; mi < 4; ++mi)
#pragma unroll
        for (int ni = 0; ni < 4; ++ni)
#pragma unroll
            for (int r = 0; r < 4; ++r) {
                int row = m0 + wm * 64 + mi * 16 + quad * 4 + r;
                int col = n0 + wn * 64 + ni * 16 + l15;
                C[(size_t)row * 512 + col] = f2bf(acc[mi][ni][r]);
            }
}

// ------------- 6. gate epilogue (fp32 out), 2 features/thread -------------
__global__ void epilogue_kernel(const u32* __restrict__ Z, const float* __restrict__ bias,
                                const float* __restrict__ hx, float* __restrict__ out, int N) {
    int t = blockIdx.x * blockDim.x + threadIdx.x;  // [0, N*64)
    if (t >= N * 64) return;
    int n = t >> 6, l = t & 63;
    const u32* z = Z + (size_t)n * 256;
    const float2* b2 = (const float2*)bias;
    u32 wr = z[l], wu = z[64 + l], wcx = z[128 + l], wch = z[192 + l];
    float2 br = b2[l], bu = b2[64 + l], bcx = b2[128 + l], bch = b2[192 + l];
    float2 h = ((const float2*)hx)[t];
    float r0 = sigmoidf_(bflo(wr) + br.x);
    float r1 = sigmoidf_(bfhi(wr) + br.y);
    float u0 = sigmoidf_(bflo(wu) + bu.x);
    float u1 = sigmoidf_(bfhi(wu) + bu.y);
    float c0 = sigmoidf_((bflo(wcx) + bcx.x) + (bflo(wch) + bch.x) * r0);
    float c1 = sigmoidf_((bfhi(wcx) + bcx.y) + (bfhi(wch) + bch.y) * r1);
    float2 o;
    o.x = u0 * h.x + (1.0f - u0) * c0;
    o.y = u1 * h.y + (1.0f - u1) * c1;
    ((float2*)out)[t] = o;
}

extern "C" void kernel_launch(void* const* d_in, const int* in_sizes, int n_in,
                              void* d_out, int out_size, void* d_ws, size_t ws_size,
                              hipStream_t stream) {
    const int* ei = (const int*)d_in[0];
    int E = in_sizes[0] / 2;
    const float* x = (const float*)d_in[1];
    const float* hx = (const float*)d_in[2];
    int N = in_sizes[1] / F_IN;
    const float* Wrx = (const float*)d_in[3];
    const float* brx = (const float*)d_in[4];
    const float* Wrh = (const float*)d_in[5];
    const float* brh = (const float*)d_in[6];
    const float* Wux = (const float*)d_in[7];
    const float* bux = (const float*)d_in[8];
    const float* Wuh = (const float*)d_in[9];
    const float* buh = (const float*)d_in[10];
    const float* Wcx = (const float*)d_in[11];
    const float* bcx = (const float*)d_in[12];
    const float* Wch = (const float*)d_in[13];
    const float* bch = (const float*)d_in[14];

    int Mpad = ((N + 127) / 128) * 128;

    char* ws = (char*)d_ws;
    size_t off = 0;
    auto alloc = [&](size_t bytes) {
        size_t o = off;
        off = (off + bytes + 255) & ~(size_t)255;
        return o;
    };
    int* counts = (int*)(ws + alloc((size_t)N * 4));
    int* cursor = (int*)(ws + alloc((size_t)N * 4));
    int* row_ptr = (int*)(ws + alloc((size_t)(N + 1) * 4));
    float* norm = (float*)(ws + alloc((size_t)N * 4));
    int* esrc = (int*)(ws + alloc((size_t)E * 4));
    u16* WT = (u16*)(ws + alloc((size_t)512 * 512 * 2));
    float* bias = (float*)(ws + alloc((size_t)512 * 4));
    u16* Zin = (u16*)(ws + alloc((size_t)Mpad * 512 * 2));
    u16* Zout = (u16*)(ws + alloc((size_t)Mpad * 512 * 2));
    (void)ws_size;

    int BC = (E + 255) / 256;
    int BV = (N * 64 + 255) / 256;
    int BP = (512 * 512) / 256;

    hipMemsetAsync(counts, 0, (size_t)N * 4, stream);
    setup_kernel<<<BC + BV + BP, 256, 0, stream>>>(ei + E, E, counts, x, hx, (u32*)Zin, N,
                                                   Wrx, Wrh, Wux, Wuh, Wcx, Wch,
                                                   brx, brh, bux, buh, bcx, bch,
                                                   WT, bias, BC, BV);
    scan_kernel<<<1, 1024, 0, stream>>>(counts, row_ptr, cursor, norm, N);
    fill_kernel<<<(E + 255) / 256, 256, 0, stream>>>(ei, ei + E, E, cursor, esrc);
    agg_kernel<<<(N + 3) / 4, 256, 0, stream>>>(row_ptr, esrc, norm, (u32*)Zin, N);
    dim3 ggrid(Mpad / 128, 4);
    gemm_kernel<<<ggrid, 256, 0, stream>>>(Zin, WT, Zout, Mpad);
    epilogue_kernel<<<((size_t)N * 64 + 255) / 256, 256, 0, stream>>>((const u32*)Zout, bias, hx,
                                                                      (float*)d_out, N);
}

// Round 4
// 494.369 us; speedup vs baseline: 1.3957x; 1.2410x over previous
//
#include <hip/hip_runtime.h>
#include <hip/hip_bf16.h>

// GConvGRU (ChebConv K=2), fp32 in/out, bf16 MFMA internally.
// K-layout of Zin rows: [x | hx | px | ph] (512 bf16 = 1 KB per node) so the
// gather source (x|hx) is one contiguous 512 B block per node.
// Pipeline: memset -> setup(count+convert+prep) -> scanA/B/C -> fill -> agg -> gemm -> epilogue

typedef unsigned short u16;
typedef unsigned int u32;
typedef __attribute__((ext_vector_type(8))) __bf16 bf16x8;
typedef __attribute__((ext_vector_type(4))) float f32x4;

#define F_IN 128
#define HID 128

__device__ __forceinline__ u16 f2bf(float f) {
    u32 u;
    __builtin_memcpy(&u, &f, 4);
    u = (u + 0x7fffu + ((u >> 16) & 1u)) >> 16;
    return (u16)u;
}
__device__ __forceinline__ float bflo(u32 w) {
    u32 u = w << 16;
    float f;
    __builtin_memcpy(&f, &u, 4);
    return f;
}
__device__ __forceinline__ float bfhi(u32 w) {
    u32 u = w & 0xffff0000u;
    float f;
    __builtin_memcpy(&f, &u, 4);
    return f;
}
__device__ __forceinline__ u32 packbf(float a, float b) {
    return ((u32)f2bf(b) << 16) | (u32)f2bf(a);
}
__device__ __forceinline__ float sigmoidf_(float x) {
    return 1.0f / (1.0f + __expf(-x));
}

__device__ __forceinline__ void async_copy16(void* lds, const void* gptr) {
    __builtin_amdgcn_global_load_lds(
        (__attribute__((address_space(1))) void*)gptr,
        (__attribute__((address_space(3))) void*)lds,
        16, 0, 0);
}

// ------------- 1. fused setup: degree count | x,hx->bf16 into Zin | weight prepack -------------
__global__ void setup_kernel(const int* __restrict__ dst, int E, int* __restrict__ counts,
                             const float* __restrict__ x, const float* __restrict__ hx,
                             u32* __restrict__ zin, int N,
                             const float* __restrict__ Wrx, const float* __restrict__ Wrh,
                             const float* __restrict__ Wux, const float* __restrict__ Wuh,
                             const float* __restrict__ Wcx, const float* __restrict__ Wch,
                             const float* __restrict__ brx, const float* __restrict__ brh,
                             const float* __restrict__ bux, const float* __restrict__ buh,
                             const float* __restrict__ bcx, const float* __restrict__ bch,
                             u16* __restrict__ WT, float* __restrict__ bias,
                             int BC, int BV) {
    int bid = blockIdx.x;
    if (bid < BC) {
        int i = bid * 256 + threadIdx.x;
        if (i < E) atomicAdd(&counts[dst[i]], 1);
    } else if (bid < BC + BV) {
        int t = (bid - BC) * 256 + threadIdx.x;  // [0, N*64)
        if (t < N * 64) {
            int n = t >> 6, l = t & 63;
            float2 vx = ((const float2*)x)[t];
            float2 vh = ((const float2*)hx)[t];
            zin[(size_t)n * 256 + l] = packbf(vx.x, vx.y);        // x slot [0,64)
            zin[(size_t)n * 256 + 64 + l] = packbf(vh.x, vh.y);   // hx slot [64,128)
        }
    } else {
        int t = (bid - BC - BV) * 256 + threadIdx.x;  // [0, 512*512)
        int c = t >> 9, k = t & 511;
        int part = c >> 7, c0 = c & 127;
        int kpart = k >> 7;
        int kf = k & 127;
        int t01 = (kpart & 2) ? 1 : 0;     // x,hx -> T0 weight; px,ph -> T1 weight
        bool isX = !(kpart & 1);           // kpart 0,2 = x-side; 1,3 = h-side
        int wi = t01 * (128 * 128) + kf * 128 + c0;
        float val = 0.0f;
        if (part == 0) val = isX ? Wrx[wi] : Wrh[wi];
        else if (part == 1) val = isX ? Wux[wi] : Wuh[wi];
        else if (part == 2) { if (isX) val = Wcx[wi]; }
        else { if (!isX) val = Wch[wi]; }
        WT[c * 512 + k] = f2bf(val);
        if (t < 512) {
            int bp = t >> 7, bc = t & 127;
            float b = 0.0f;
            if (bp == 0) b = brx[bc] + brh[bc];
            else if (bp == 1) b = bux[bc] + buh[bc];
            else if (bp == 2) b = bcx[bc];
            else b = bch[bc];
            bias[t] = b;
        }
    }
}

// ------------- 2a. block-level scan (coalesced) -------------
__global__ __launch_bounds__(1024) void scanA_kernel(const int* __restrict__ counts,
                                                     int* __restrict__ pre,
                                                     int* __restrict__ partials, int N) {
    __shared__ int buf[1024];
    int tid = threadIdx.x;
    int t = blockIdx.x * 1024 + tid;
    int v = (t < N) ? counts[t] : 0;
    buf[tid] = v;
    __syncthreads();
    for (int off = 1; off < 1024; off <<= 1) {
        int o = (tid >= off) ? buf[tid - off] : 0;
        __syncthreads();
        buf[tid] += o;
        __syncthreads();
    }
    if (t < N) pre[t] = buf[tid] - v;            // in-block exclusive prefix
    if (tid == 1023) partials[blockIdx.x] = buf[1023];
}

// ------------- 2b. scan the block totals (1 block) -------------
__global__ __launch_bounds__(1024) void scanB_kernel(int* __restrict__ partials, int NB) {
    __shared__ int buf[1024];
    int tid = threadIdx.x;
    int v = (tid < NB) ? partials[tid] : 0;
    buf[tid] = v;
    __syncthreads();
    for (int off = 1; off < 1024; off <<= 1) {
        int o = (tid >= off) ? buf[tid - off] : 0;
        __syncthreads();
        buf[tid] += o;
        __syncthreads();
    }
    if (tid < NB) partials[tid] = buf[tid] - v;  // exclusive block offsets
}

// ------------- 2c. combine + norm (coalesced) -------------
__global__ void scanC_kernel(const int* __restrict__ counts, const int* __restrict__ pre,
                             const int* __restrict__ partials, int* __restrict__ row_ptr,
                             int* __restrict__ cursor, float* __restrict__ norm, int N, int E) {
    int i = blockIdx.x * blockDim.x + threadIdx.x;
    if (i < N) {
        int r = pre[i] + partials[i >> 10];
        row_ptr[i] = r;
        cursor[i] = r;
        int c = counts[i];
        norm[i] = rsqrtf((float)(c > 1 ? c : 1));
    }
    if (i == 0) row_ptr[N] = E;
}

// ------------- 3. CSR fill -------------
__global__ void fill_kernel(const int* __restrict__ src, const int* __restrict__ dst, int E,
                            int* __restrict__ cursor, int* __restrict__ esrc) {
    int i = blockIdx.x * blockDim.x + threadIdx.x;
    if (i < E) {
        int d = dst[i];
        int slot = atomicAdd(&cursor[d], 1);
        esrc[slot] = src[i];
    }
}

// ------------- 4. wave-per-node gather-aggregate -------------
// Half-wave (32 lanes x 16 B) covers one node's contiguous x|hx 512 B block.
// 2 edges per iteration; next pair's (esrc, norm) prefetched.
__global__ __launch_bounds__(256) void agg_kernel(const int* __restrict__ row_ptr,
                                                  const int* __restrict__ esrc,
                                                  const float* __restrict__ norm,
                                                  u32* __restrict__ zin, int N) {
    int node = blockIdx.x * 4 + (threadIdx.x >> 6);
    int lane = threadIdx.x & 63;
    if (node >= N) return;
    int h = lane >> 5;     // which edge of the pair
    int li = lane & 31;    // 16 B slot within the 512 B x|hx block
    int beg = row_ptr[node], end = row_ptr[node + 1];
    const uint4* z4 = (const uint4*)zin;  // 64 uint4 per node row
    float a0 = 0.f, a1 = 0.f, a2 = 0.f, a3 = 0.f, a4 = 0.f, a5 = 0.f, a6 = 0.f, a7 = 0.f;
    if (beg < end) {
        int e = beg;
        int eq = e + h;
        int ec = eq < end ? eq : end - 1;
        int s = esrc[ec];
        float ns = (eq < end) ? norm[s] : 0.f;
        for (;;) {
            uint4 v = z4[(size_t)s * 64 + li];
            int e2 = e + 2;
            int s2 = s;
            float ns2 = 0.f;
            bool more = e2 < end;
            if (more) {
                int eq2 = e2 + h;
                int ec2 = eq2 < end ? eq2 : end - 1;
                s2 = esrc[ec2];
                ns2 = (eq2 < end) ? norm[s2] : 0.f;
            }
            a0 += bflo(v.x) * ns; a1 += bfhi(v.x) * ns;
            a2 += bflo(v.y) * ns; a3 += bfhi(v.y) * ns;
            a4 += bflo(v.z) * ns; a5 += bfhi(v.z) * ns;
            a6 += bflo(v.w) * ns; a7 += bfhi(v.w) * ns;
            if (!more) break;
            s = s2; ns = ns2; e = e2;
        }
    }
    a0 += __shfl_xor(a0, 32); a1 += __shfl_xor(a1, 32);
    a2 += __shfl_xor(a2, 32); a3 += __shfl_xor(a3, 32);
    a4 += __shfl_xor(a4, 32); a5 += __shfl_xor(a5, 32);
    a6 += __shfl_xor(a6, 32); a7 += __shfl_xor(a7, 32);
    if (lane < 32) {
        float nn = -norm[node];
        uint4 o;
        o.x = packbf(a0 * nn, a1 * nn);
        o.y = packbf(a2 * nn, a3 * nn);
        o.z = packbf(a4 * nn, a5 * nn);
        o.w = packbf(a6 * nn, a7 * nn);
        ((uint4*)zin)[(size_t)node * 64 + 32 + li] = o;  // px|ph slots [32,64)
    }
}

// ------------- 5. MFMA GEMM: Z[M,512] = A[M,512] * B^T (B stored [col][k]) -------------
__global__ __launch_bounds__(256) void gemm_kernel(const u16* __restrict__ A,
                                                   const u16* __restrict__ B,
                                                   u16* __restrict__ C, int M) {
    __shared__ __align__(16) __bf16 As[128 * 32];
    __shared__ __align__(16) __bf16 Bs[128 * 32];
    int tid = threadIdx.x;
    int wave = tid >> 6, lane = tid & 63;
    int m0 = blockIdx.x * 128;
    int n0 = blockIdx.y * 128;
    int wm = wave & 1, wn = wave >> 1;
    int quad = lane >> 4, l15 = lane & 15;

    f32x4 acc[4][4];
#pragma unroll
    for (int mi = 0; mi < 4; ++mi)
#pragma unroll
        for (int ni = 0; ni < 4; ++ni) acc[mi][ni] = (f32x4){0.f, 0.f, 0.f, 0.f};

    for (int k0 = 0; k0 < 512; k0 += 32) {
        __syncthreads();
#pragma unroll
        for (int j = 0; j < 2; ++j) {
            int chunk = wave * 2 + j;            // 0..7, 1 KB each
            int fl = chunk * 512 + lane * 8;
            int row = fl >> 5;
            int col = fl & 31;
            async_copy16(&As[chunk * 512], A + (size_t)(m0 + row) * 512 + k0 + col);
            async_copy16(&Bs[chunk * 512], B + (size_t)(n0 + row) * 512 + k0 + col);
        }
        __syncthreads();
        bf16x8 af[4], bfr[4];
#pragma unroll
        for (int mi = 0; mi < 4; ++mi)
            af[mi] = *(const bf16x8*)&As[(wm * 64 + mi * 16 + l15) * 32 + quad * 8];
#pragma unroll
        for (int ni = 0; ni < 4; ++ni)
            bfr[ni] = *(const bf16x8*)&Bs[(wn * 64 + ni * 16 + l15) * 32 + quad * 8];
#pragma unroll
        for (int mi = 0; mi < 4; ++mi)
#pragma unroll
            for (int ni = 0; ni < 4; ++ni)
                acc[mi][ni] = __builtin_amdgcn_mfma_f32_16x16x32_bf16(af[mi], bfr[ni],
                                                                      acc[mi][ni], 0, 0, 0);
    }
    // C/D layout: col = lane&15, row = quad*4 + reg
#pragma unroll
    for (int mi = 0; mi < 4; ++mi)
#pragma unroll
        for (int ni = 0; ni < 4; ++ni)
#pragma unroll
            for (int r = 0; r < 4; ++r) {
                int row = m0 + wm * 64 + mi * 16 + quad * 4 + r;
                int col = n0 + wn * 64 + ni * 16 + l15;
                C[(size_t)row * 512 + col] = f2bf(acc[mi][ni][r]);
            }
}

// ------------- 6. gate epilogue (fp32 out), 2 features/thread -------------
__global__ void epilogue_kernel(const u32* __restrict__ Z, const float* __restrict__ bias,
                                const float* __restrict__ hx, float* __restrict__ out, int N) {
    int t = blockIdx.x * blockDim.x + threadIdx.x;  // [0, N*64)
    if (t >= N * 64) return;
    int n = t >> 6, l = t & 63;
    const u32* z = Z + (size_t)n * 256;
    const float2* b2 = (const float2*)bias;
    u32 wr = z[l], wu = z[64 + l], wcx = z[128 + l], wch = z[192 + l];
    float2 br = b2[l], bu = b2[64 + l], bcx = b2[128 + l], bch = b2[192 + l];
    float2 h = ((const float2*)hx)[t];
    float r0 = sigmoidf_(bflo(wr) + br.x);
    float r1 = sigmoidf_(bfhi(wr) + br.y);
    float u0 = sigmoidf_(bflo(wu) + bu.x);
    float u1 = sigmoidf_(bfhi(wu) + bu.y);
    float c0 = sigmoidf_((bflo(wcx) + bcx.x) + (bflo(wch) + bch.x) * r0);
    float c1 = sigmoidf_((bfhi(wcx) + bcx.y) + (bfhi(wch) + bch.y) * r1);
    float2 o;
    o.x = u0 * h.x + (1.0f - u0) * c0;
    o.y = u1 * h.y + (1.0f - u1) * c1;
    ((float2*)out)[t] = o;
}

extern "C" void kernel_launch(void* const* d_in, const int* in_sizes, int n_in,
                              void* d_out, int out_size, void* d_ws, size_t ws_size,
                              hipStream_t stream) {
    const int* ei = (const int*)d_in[0];
    int E = in_sizes[0] / 2;
    const float* x = (const float*)d_in[1];
    const float* hx = (const float*)d_in[2];
    int N = in_sizes[1] / F_IN;
    const float* Wrx = (const float*)d_in[3];
    const float* brx = (const float*)d_in[4];
    const float* Wrh = (const float*)d_in[5];
    const float* brh = (const float*)d_in[6];
    const float* Wux = (const float*)d_in[7];
    const float* bux = (const float*)d_in[8];
    const float* Wuh = (const float*)d_in[9];
    const float* buh = (const float*)d_in[10];
    const float* Wcx = (const float*)d_in[11];
    const float* bcx = (const float*)d_in[12];
    const float* Wch = (const float*)d_in[13];
    const float* bch = (const float*)d_in[14];

    int Mpad = ((N + 127) / 128) * 128;

    char* ws = (char*)d_ws;
    size_t off = 0;
    auto alloc = [&](size_t bytes) {
        size_t o = off;
        off = (off + bytes + 255) & ~(size_t)255;
        return o;
    };
    int* counts = (int*)(ws + alloc((size_t)N * 4));
    int* cursor = (int*)(ws + alloc((size_t)N * 4));
    int* row_ptr = (int*)(ws + alloc((size_t)(N + 1) * 4));
    float* norm = (float*)(ws + alloc((size_t)N * 4));
    int* pre = (int*)(ws + alloc((size_t)N * 4));
    int* partials = (int*)(ws + alloc((size_t)1024 * 4));
    int* esrc = (int*)(ws + alloc((size_t)E * 4));
    u16* WT = (u16*)(ws + alloc((size_t)512 * 512 * 2));
    float* bias = (float*)(ws + alloc((size_t)512 * 4));
    u16* Zin = (u16*)(ws + alloc((size_t)Mpad * 512 * 2));
    u16* Zout = (u16*)(ws + alloc((size_t)Mpad * 512 * 2));
    (void)ws_size;

    int BC = (E + 255) / 256;
    int BV = (N * 64 + 255) / 256;
    int BP = (512 * 512) / 256;
    int NB = (N + 1023) / 1024;

    hipMemsetAsync(counts, 0, (size_t)N * 4, stream);
    setup_kernel<<<BC + BV + BP, 256, 0, stream>>>(ei + E, E, counts, x, hx, (u32*)Zin, N,
                                                   Wrx, Wrh, Wux, Wuh, Wcx, Wch,
                                                   brx, brh, bux, buh, bcx, bch,
                                                   WT, bias, BC, BV);
    scanA_kernel<<<NB, 1024, 0, stream>>>(counts, pre, partials, N);
    scanB_kernel<<<1, 1024, 0, stream>>>(partials, NB);
    scanC_kernel<<<(N + 255) / 256, 256, 0, stream>>>(counts, pre, partials, row_ptr,
                                                      cursor, norm, N, E);
    fill_kernel<<<(E + 255) / 256, 256, 0, stream>>>(ei, ei + E, E, cursor, esrc);
    agg_kernel<<<(N + 3) / 4, 256, 0, stream>>>(row_ptr, esrc, norm, (u32*)Zin, N);
    dim3 ggrid(Mpad / 128, 4);
    gemm_kernel<<<ggrid, 256, 0, stream>>>(Zin, WT, Zout, Mpad);
    epilogue_kernel<<<((size_t)N * 64 + 255) / 256, 256, 0, stream>>>((const u32*)Zout, bias, hx,
                                                                      (float*)d_out, N);
}

// Round 5
// 446.746 us; speedup vs baseline: 1.5445x; 1.1066x over previous
//
#include <hip/hip_runtime.h>
#include <hip/hip_bf16.h>

// GConvGRU (ChebConv K=2), fp32 in/out, bf16 MFMA internally.
// Zin row K-layout: [x | hx | px | ph] (512 bf16 = 1 KB/node); gather source
// (x|hx) is one contiguous 512 B block per node.
// Pipeline: memset -> setup(count+convert+prep) -> scanA/B/C -> fill(binned) -> agg -> gemm -> epilogue

typedef unsigned short u16;
typedef unsigned int u32;
typedef __attribute__((ext_vector_type(8))) __bf16 bf16x8;
typedef __attribute__((ext_vector_type(4))) float f32x4;

#define F_IN 128
#define HID 128

__device__ __forceinline__ u16 f2bf(float f) {
    u32 u;
    __builtin_memcpy(&u, &f, 4);
    u = (u + 0x7fffu + ((u >> 16) & 1u)) >> 16;
    return (u16)u;
}
__device__ __forceinline__ float bflo(u32 w) {
    u32 u = w << 16;
    float f;
    __builtin_memcpy(&f, &u, 4);
    return f;
}
__device__ __forceinline__ float bfhi(u32 w) {
    u32 u = w & 0xffff0000u;
    float f;
    __builtin_memcpy(&f, &u, 4);
    return f;
}
__device__ __forceinline__ u32 packbf(float a, float b) {
    return ((u32)f2bf(b) << 16) | (u32)f2bf(a);
}
__device__ __forceinline__ float sigmoidf_(float x) {
    return 1.0f / (1.0f + __expf(-x));
}

__device__ __forceinline__ void async_copy16(void* lds, const void* gptr) {
    __builtin_amdgcn_global_load_lds(
        (__attribute__((address_space(1))) void*)gptr,
        (__attribute__((address_space(3))) void*)lds,
        16, 0, 0);
}

// ------------- 1. fused setup: degree count | x,hx->bf16 into Zin | weight prepack -------------
__global__ void setup_kernel(const int* __restrict__ dst, int E, int* __restrict__ counts,
                             const float* __restrict__ x, const float* __restrict__ hx,
                             u32* __restrict__ zin, int N,
                             const float* __restrict__ Wrx, const float* __restrict__ Wrh,
                             const float* __restrict__ Wux, const float* __restrict__ Wuh,
                             const float* __restrict__ Wcx, const float* __restrict__ Wch,
                             const float* __restrict__ brx, const float* __restrict__ brh,
                             const float* __restrict__ bux, const float* __restrict__ buh,
                             const float* __restrict__ bcx, const float* __restrict__ bch,
                             u16* __restrict__ WT, float* __restrict__ bias,
                             int BC, int BV) {
    int bid = blockIdx.x;
    if (bid < BC) {
        int i = bid * 256 + threadIdx.x;
        if (i < E) atomicAdd(&counts[dst[i]], 1);
    } else if (bid < BC + BV) {
        int t = (bid - BC) * 256 + threadIdx.x;  // [0, N*64)
        if (t < N * 64) {
            int n = t >> 6, l = t & 63;
            float2 vx = ((const float2*)x)[t];
            float2 vh = ((const float2*)hx)[t];
            zin[(size_t)n * 256 + l] = packbf(vx.x, vx.y);        // x slot [0,64)
            zin[(size_t)n * 256 + 64 + l] = packbf(vh.x, vh.y);   // hx slot [64,128)
        }
    } else {
        int t = (bid - BC - BV) * 256 + threadIdx.x;  // [0, 512*512)
        int c = t >> 9, k = t & 511;
        int part = c >> 7, c0 = c & 127;
        int kpart = k >> 7;
        int kf = k & 127;
        int t01 = (kpart & 2) ? 1 : 0;     // x,hx -> T0 weight; px,ph -> T1 weight
        bool isX = !(kpart & 1);           // kpart 0,2 = x-side; 1,3 = h-side
        int wi = t01 * (128 * 128) + kf * 128 + c0;
        float val = 0.0f;
        if (part == 0) val = isX ? Wrx[wi] : Wrh[wi];
        else if (part == 1) val = isX ? Wux[wi] : Wuh[wi];
        else if (part == 2) { if (isX) val = Wcx[wi]; }
        else { if (!isX) val = Wch[wi]; }
        WT[c * 512 + k] = f2bf(val);
        if (t < 512) {
            int bp = t >> 7, bc = t & 127;
            float b = 0.0f;
            if (bp == 0) b = brx[bc] + brh[bc];
            else if (bp == 1) b = bux[bc] + buh[bc];
            else if (bp == 2) b = bcx[bc];
            else b = bch[bc];
            bias[t] = b;
        }
    }
}

// ------------- 2a. block-level scan (coalesced) -------------
__global__ __launch_bounds__(1024) void scanA_kernel(const int* __restrict__ counts,
                                                     int* __restrict__ pre,
                                                     int* __restrict__ partials, int N) {
    __shared__ int buf[1024];
    int tid = threadIdx.x;
    int t = blockIdx.x * 1024 + tid;
    int v = (t < N) ? counts[t] : 0;
    buf[tid] = v;
    __syncthreads();
    for (int off = 1; off < 1024; off <<= 1) {
        int o = (tid >= off) ? buf[tid - off] : 0;
        __syncthreads();
        buf[tid] += o;
        __syncthreads();
    }
    if (t < N) pre[t] = buf[tid] - v;
    if (tid == 1023) partials[blockIdx.x] = buf[1023];
}

// ------------- 2b. scan the block totals (1 block) -------------
__global__ __launch_bounds__(1024) void scanB_kernel(int* __restrict__ partials, int NB) {
    __shared__ int buf[1024];
    int tid = threadIdx.x;
    int v = (tid < NB) ? partials[tid] : 0;
    buf[tid] = v;
    __syncthreads();
    for (int off = 1; off < 1024; off <<= 1) {
        int o = (tid >= off) ? buf[tid - off] : 0;
        __syncthreads();
        buf[tid] += o;
        __syncthreads();
    }
    if (tid < NB) partials[tid] = buf[tid] - v;
}

// ------------- 2c. combine + norm (coalesced) -------------
__global__ void scanC_kernel(const int* __restrict__ counts, const int* __restrict__ pre,
                             const int* __restrict__ partials, int* __restrict__ row_ptr,
                             int* __restrict__ cursor, float* __restrict__ norm, int N, int E) {
    int i = blockIdx.x * blockDim.x + threadIdx.x;
    if (i < N) {
        int r = pre[i] + partials[i >> 10];
        row_ptr[i] = r;
        cursor[i] = r;
        int c = counts[i];
        norm[i] = rsqrtf((float)(c > 1 ? c : 1));
    }
    if (i == 0) row_ptr[N] = E;
}

// ------------- 3. CSR fill, dst-range binned for XCD-local writes -------------
// range = blockIdx.x & 7 (round-robin block->XCD heuristic): all writers of one
// contiguous esrc slot range share an L2, so 4 B stores coalesce in-cache.
__global__ __launch_bounds__(256) void fill_kernel(const int* __restrict__ src,
                                                   const int* __restrict__ dst, int E,
                                                   int* __restrict__ cursor,
                                                   int* __restrict__ esrc,
                                                   int nodesPerRange, int edgesPerChunk) {
    int range = blockIdx.x & 7;
    int chunk = blockIdx.x >> 3;
    int lo = range * nodesPerRange;
    int beg = chunk * edgesPerChunk;
    int end = beg + edgesPerChunk;
    if (end > E) end = E;
    for (int i = beg + (int)threadIdx.x * 4; i < end; i += 256 * 4) {
        if (i + 4 <= end) {
            int4 s4 = *(const int4*)(src + i);
            int4 d4 = *(const int4*)(dst + i);
#pragma unroll
            for (int j = 0; j < 4; ++j) {
                int d = (j == 0) ? d4.x : (j == 1) ? d4.y : (j == 2) ? d4.z : d4.w;
                int s = (j == 0) ? s4.x : (j == 1) ? s4.y : (j == 2) ? s4.z : s4.w;
                if ((unsigned)(d - lo) < (unsigned)nodesPerRange) {
                    int slot = atomicAdd(&cursor[d], 1);
                    esrc[slot] = s;
                }
            }
        } else {
            for (int j = i; j < end; ++j) {
                int d = dst[j];
                if ((unsigned)(d - lo) < (unsigned)nodesPerRange) {
                    int slot = atomicAdd(&cursor[d], 1);
                    esrc[slot] = src[j];
                }
            }
        }
    }
}

// ------------- 4. wave-per-node gather-aggregate, 4 edges/iter -------------
// Half-wave (32 lanes x 16 B) covers one node's contiguous x|hx 512 B block.
// Each half handles 2 edges per iteration (2 independent gathers in flight);
// next group's (esrc, norm) prefetched.
__global__ __launch_bounds__(256) void agg_kernel(const int* __restrict__ row_ptr,
                                                  const int* __restrict__ esrc,
                                                  const float* __restrict__ norm,
                                                  u32* __restrict__ zin, int N) {
    int node = blockIdx.x * 4 + (threadIdx.x >> 6);
    int lane = threadIdx.x & 63;
    if (node >= N) return;
    int h = lane >> 5;     // which half-wave
    int li = lane & 31;    // 16 B slot within the 512 B x|hx block
    int beg = row_ptr[node], end = row_ptr[node + 1];
    const uint4* z4 = (const uint4*)zin;  // 64 uint4 per node row
    float a0 = 0.f, a1 = 0.f, a2 = 0.f, a3 = 0.f, a4 = 0.f, a5 = 0.f, a6 = 0.f, a7 = 0.f;
    if (beg < end) {
        int e = beg;
        int s0, s1;
        float n0, n1;
        {
            int q0 = e + h * 2, q1 = q0 + 1;
            int c0 = q0 < end ? q0 : end - 1;
            int c1 = q1 < end ? q1 : end - 1;
            s0 = esrc[c0]; s1 = esrc[c1];
            n0 = (q0 < end) ? norm[s0] : 0.f;
            n1 = (q1 < end) ? norm[s1] : 0.f;
        }
        for (;;) {
            uint4 v0 = z4[(size_t)s0 * 64 + li];
            uint4 v1 = z4[(size_t)s1 * 64 + li];
            bool more = (e + 4) < end;
            int t0 = s0, t1 = s1;
            float m0 = 0.f, m1 = 0.f;
            if (more) {
                int q0 = e + 4 + h * 2, q1 = q0 + 1;
                int c0 = q0 < end ? q0 : end - 1;
                int c1 = q1 < end ? q1 : end - 1;
                t0 = esrc[c0]; t1 = esrc[c1];
                m0 = (q0 < end) ? norm[t0] : 0.f;
                m1 = (q1 < end) ? norm[t1] : 0.f;
            }
            a0 += bflo(v0.x) * n0; a1 += bfhi(v0.x) * n0;
            a2 += bflo(v0.y) * n0; a3 += bfhi(v0.y) * n0;
            a4 += bflo(v0.z) * n0; a5 += bfhi(v0.z) * n0;
            a6 += bflo(v0.w) * n0; a7 += bfhi(v0.w) * n0;
            a0 += bflo(v1.x) * n1; a1 += bfhi(v1.x) * n1;
            a2 += bflo(v1.y) * n1; a3 += bfhi(v1.y) * n1;
            a4 += bflo(v1.z) * n1; a5 += bfhi(v1.z) * n1;
            a6 += bflo(v1.w) * n1; a7 += bfhi(v1.w) * n1;
            if (!more) break;
            s0 = t0; s1 = t1; n0 = m0; n1 = m1; e += 4;
        }
    }
    a0 += __shfl_xor(a0, 32); a1 += __shfl_xor(a1, 32);
    a2 += __shfl_xor(a2, 32); a3 += __shfl_xor(a3, 32);
    a4 += __shfl_xor(a4, 32); a5 += __shfl_xor(a5, 32);
    a6 += __shfl_xor(a6, 32); a7 += __shfl_xor(a7, 32);
    if (lane < 32) {
        float nn = -norm[node];
        uint4 o;
        o.x = packbf(a0 * nn, a1 * nn);
        o.y = packbf(a2 * nn, a3 * nn);
        o.z = packbf(a4 * nn, a5 * nn);
        o.w = packbf(a6 * nn, a7 * nn);
        ((uint4*)zin)[(size_t)node * 64 + 32 + li] = o;  // px|ph slots [32,64)
    }
}

// ------------- 5. MFMA GEMM: Z[M,512] = A[M,512] * B^T (B stored [col][k]) -------------
__global__ __launch_bounds__(256) void gemm_kernel(const u16* __restrict__ A,
                                                   const u16* __restrict__ B,
                                                   u16* __restrict__ C, int M) {
    __shared__ __align__(16) __bf16 As[128 * 32];
    __shared__ __align__(16) __bf16 Bs[128 * 32];
    int tid = threadIdx.x;
    int wave = tid >> 6, lane = tid & 63;
    int m0 = blockIdx.x * 128;
    int n0 = blockIdx.y * 128;
    int wm = wave & 1, wn = wave >> 1;
    int quad = lane >> 4, l15 = lane & 15;

    f32x4 acc[4][4];
#pragma unroll
    for (int mi = 0; mi < 4; ++mi)
#pragma unroll
        for (int ni = 0; ni < 4; ++ni) acc[mi][ni] = (f32x4){0.f, 0.f, 0.f, 0.f};

    for (int k0 = 0; k0 < 512; k0 += 32) {
        __syncthreads();
#pragma unroll
        for (int j = 0; j < 2; ++j) {
            int chunk = wave * 2 + j;            // 0..7, 1 KB each
            int fl = chunk * 512 + lane * 8;
            int row = fl >> 5;
            int col = fl & 31;
            async_copy16(&As[chunk * 512], A + (size_t)(m0 + row) * 512 + k0 + col);
            async_copy16(&Bs[chunk * 512], B + (size_t)(n0 + row) * 512 + k0 + col);
        }
        __syncthreads();
        bf16x8 af[4], bfr[4];
#pragma unroll
        for (int mi = 0; mi < 4; ++mi)
            af[mi] = *(const bf16x8*)&As[(wm * 64 + mi * 16 + l15) * 32 + quad * 8];
#pragma unroll
        for (int ni = 0; ni < 4; ++ni)
            bfr[ni] = *(const bf16x8*)&Bs[(wn * 64 + ni * 16 + l15) * 32 + quad * 8];
#pragma unroll
        for (int mi = 0; mi < 4; ++mi)
#pragma unroll
            for (int ni = 0; ni < 4; ++ni)
                acc[mi][ni] = __builtin_amdgcn_mfma_f32_16x16x32_bf16(af[mi], bfr[ni],
                                                                      acc[mi][ni], 0, 0, 0);
    }
    // C/D layout: col = lane&15, row = quad*4 + reg
#pragma unroll
    for (int mi = 0; mi < 4; ++mi)
#pragma unroll
        for (int ni = 0; ni < 4; ++ni)
#pragma unroll
            for (int r = 0; r < 4; ++r) {
                int row = m0 + wm * 64 + mi * 16 + quad * 4 + r;
                int col = n0 + wn * 64 + ni * 16 + l15;
                C[(size_t)row * 512 + col] = f2bf(acc[mi][ni][r]);
            }
}

// ------------- 6. gate epilogue (fp32 out), 2 features/thread -------------
__global__ void epilogue_kernel(const u32* __restrict__ Z, const float* __restrict__ bias,
                                const float* __restrict__ hx, float* __restrict__ out, int N) {
    int t = blockIdx.x * blockDim.x + threadIdx.x;  // [0, N*64)
    if (t >= N * 64) return;
    int n = t >> 6, l = t & 63;
    const u32* z = Z + (size_t)n * 256;
    const float2* b2 = (const float2*)bias;
    u32 wr = z[l], wu = z[64 + l], wcx = z[128 + l], wch = z[192 + l];
    float2 br = b2[l], bu = b2[64 + l], bcx = b2[128 + l], bch = b2[192 + l];
    float2 h = ((const float2*)hx)[t];
    float r0 = sigmoidf_(bflo(wr) + br.x);
    float r1 = sigmoidf_(bfhi(wr) + br.y);
    float u0 = sigmoidf_(bflo(wu) + bu.x);
    float u1 = sigmoidf_(bfhi(wu) + bu.y);
    float c0 = sigmoidf_((bflo(wcx) + bcx.x) + (bflo(wch) + bch.x) * r0);
    float c1 = sigmoidf_((bfhi(wcx) + bcx.y) + (bfhi(wch) + bch.y) * r1);
    float2 o;
    o.x = u0 * h.x + (1.0f - u0) * c0;
    o.y = u1 * h.y + (1.0f - u1) * c1;
    ((float2*)out)[t] = o;
}

extern "C" void kernel_launch(void* const* d_in, const int* in_sizes, int n_in,
                              void* d_out, int out_size, void* d_ws, size_t ws_size,
                              hipStream_t stream) {
    const int* ei = (const int*)d_in[0];
    int E = in_sizes[0] / 2;
    const float* x = (const float*)d_in[1];
    const float* hx = (const float*)d_in[2];
    int N = in_sizes[1] / F_IN;
    const float* Wrx = (const float*)d_in[3];
    const float* brx = (const float*)d_in[4];
    const float* Wrh = (const float*)d_in[5];
    const float* brh = (const float*)d_in[6];
    const float* Wux = (const float*)d_in[7];
    const float* bux = (const float*)d_in[8];
    const float* Wuh = (const float*)d_in[9];
    const float* buh = (const float*)d_in[10];
    const float* Wcx = (const float*)d_in[11];
    const float* bcx = (const float*)d_in[12];
    const float* Wch = (const float*)d_in[13];
    const float* bch = (const float*)d_in[14];

    int Mpad = ((N + 127) / 128) * 128;

    char* ws = (char*)d_ws;
    size_t off = 0;
    auto alloc = [&](size_t bytes) {
        size_t o = off;
        off = (off + bytes + 255) & ~(size_t)255;
        return o;
    };
    int* counts = (int*)(ws + alloc((size_t)N * 4));
    int* cursor = (int*)(ws + alloc((size_t)N * 4));
    int* row_ptr = (int*)(ws + alloc((size_t)(N + 1) * 4));
    float* norm = (float*)(ws + alloc((size_t)N * 4));
    int* pre = (int*)(ws + alloc((size_t)N * 4));
    int* partials = (int*)(ws + alloc((size_t)1024 * 4));
    int* esrc = (int*)(ws + alloc((size_t)E * 4));
    u16* WT = (u16*)(ws + alloc((size_t)512 * 512 * 2));
    float* bias = (float*)(ws + alloc((size_t)512 * 4));
    u16* Zin = (u16*)(ws + alloc((size_t)Mpad * 512 * 2));
    u16* Zout = (u16*)(ws + alloc((size_t)Mpad * 512 * 2));
    (void)ws_size;

    int BC = (E + 255) / 256;
    int BV = (N * 64 + 255) / 256;
    int BP = (512 * 512) / 256;
    int NB = (N + 1023) / 1024;

    hipMemsetAsync(counts, 0, (size_t)N * 4, stream);
    setup_kernel<<<BC + BV + BP, 256, 0, stream>>>(ei + E, E, counts, x, hx, (u32*)Zin, N,
                                                   Wrx, Wrh, Wux, Wuh, Wcx, Wch,
                                                   brx, brh, bux, buh, bcx, bch,
                                                   WT, bias, BC, BV);
    scanA_kernel<<<NB, 1024, 0, stream>>>(counts, pre, partials, N);
    scanB_kernel<<<1, 1024, 0, stream>>>(partials, NB);
    scanC_kernel<<<(N + 255) / 256, 256, 0, stream>>>(counts, pre, partials, row_ptr,
                                                      cursor, norm, N, E);
    const int numChunks = 128;
    int edgesPerChunk = (((E + numChunks - 1) / numChunks) + 1023) & ~1023;
    int nodesPerRange = (N + 7) / 8;
    fill_kernel<<<numChunks * 8, 256, 0, stream>>>(ei, ei + E, E, cursor, esrc,
                                                   nodesPerRange, edgesPerChunk);
    agg_kernel<<<(N + 3) / 4, 256, 0, stream>>>(row_ptr, esrc, norm, (u32*)Zin, N);
    dim3 ggrid(Mpad / 128, 4);
    gemm_kernel<<<ggrid, 256, 0, stream>>>(Zin, WT, Zout, Mpad);
    epilogue_kernel<<<((size_t)N * 64 + 255) / 256, 256, 0, stream>>>((const u32*)Zout, bias, hx,
                                                                      (float*)d_out, N);
}

// Round 6
// 397.410 us; speedup vs baseline: 1.7363x; 1.1241x over previous
//
#include <hip/hip_runtime.h>
#include <hip/hip_bf16.h>

// GConvGRU (ChebConv K=2), fp32 in/out; bf16 MFMA GEMM; fp8 gather path.
// Zin row K-layout: [x | hx | px | ph] (512 bf16 = 1 KB/node).
// xf8[n]: 256 fp8 bytes = concat(x[n],hx[n]) * norm[n]  (prescaled!)
// Pipeline: memset -> setup -> scanA/B/C -> (f8conv | fill) -> agg -> gemm -> epilogue

typedef unsigned short u16;
typedef unsigned int u32;
typedef __attribute__((ext_vector_type(8))) __bf16 bf16x8;
typedef __attribute__((ext_vector_type(4))) float f32x4;
typedef __attribute__((ext_vector_type(2))) float f32x2;

#define F_IN 128
#define HID 128

__device__ __forceinline__ u16 f2bf(float f) {
    u32 u;
    __builtin_memcpy(&u, &f, 4);
    u = (u + 0x7fffu + ((u >> 16) & 1u)) >> 16;
    return (u16)u;
}
__device__ __forceinline__ float bflo(u32 w) {
    u32 u = w << 16;
    float f;
    __builtin_memcpy(&f, &u, 4);
    return f;
}
__device__ __forceinline__ float bfhi(u32 w) {
    u32 u = w & 0xffff0000u;
    float f;
    __builtin_memcpy(&f, &u, 4);
    return f;
}
__device__ __forceinline__ u32 packbf(float a, float b) {
    return ((u32)f2bf(b) << 16) | (u32)f2bf(a);
}
__device__ __forceinline__ float sigmoidf_(float x) {
    return 1.0f / (1.0f + __expf(-x));
}

__device__ __forceinline__ void async_copy16(void* lds, const void* gptr) {
    __builtin_amdgcn_global_load_lds(
        (__attribute__((address_space(1))) void*)gptr,
        (__attribute__((address_space(3))) void*)lds,
        16, 0, 0);
}

// ------------- 1. fused setup: degree count | x,hx->bf16 into Zin | weight prepack -------------
__global__ void setup_kernel(const int* __restrict__ dst, int E, int* __restrict__ counts,
                             const float* __restrict__ x, const float* __restrict__ hx,
                             u32* __restrict__ zin, int N,
                             const float* __restrict__ Wrx, const float* __restrict__ Wrh,
                             const float* __restrict__ Wux, const float* __restrict__ Wuh,
                             const float* __restrict__ Wcx, const float* __restrict__ Wch,
                             const float* __restrict__ brx, const float* __restrict__ brh,
                             const float* __restrict__ bux, const float* __restrict__ buh,
                             const float* __restrict__ bcx, const float* __restrict__ bch,
                             u16* __restrict__ WT, float* __restrict__ bias,
                             int BC, int BV) {
    int bid = blockIdx.x;
    if (bid < BC) {
        int i = bid * 256 + threadIdx.x;
        if (i < E) atomicAdd(&counts[dst[i]], 1);
    } else if (bid < BC + BV) {
        int t = (bid - BC) * 256 + threadIdx.x;  // [0, N*64)
        if (t < N * 64) {
            int n = t >> 6, l = t & 63;
            float2 vx = ((const float2*)x)[t];
            float2 vh = ((const float2*)hx)[t];
            zin[(size_t)n * 256 + l] = packbf(vx.x, vx.y);        // x slot [0,64)
            zin[(size_t)n * 256 + 64 + l] = packbf(vh.x, vh.y);   // hx slot [64,128)
        }
    } else {
        int t = (bid - BC - BV) * 256 + threadIdx.x;  // [0, 512*512)
        int c = t >> 9, k = t & 511;
        int part = c >> 7, c0 = c & 127;
        int kpart = k >> 7;
        int kf = k & 127;
        int t01 = (kpart & 2) ? 1 : 0;     // x,hx -> T0 weight; px,ph -> T1 weight
        bool isX = !(kpart & 1);           // kpart 0,2 = x-side; 1,3 = h-side
        int wi = t01 * (128 * 128) + kf * 128 + c0;
        float val = 0.0f;
        if (part == 0) val = isX ? Wrx[wi] : Wrh[wi];
        else if (part == 1) val = isX ? Wux[wi] : Wuh[wi];
        else if (part == 2) { if (isX) val = Wcx[wi]; }
        else { if (!isX) val = Wch[wi]; }
        WT[c * 512 + k] = f2bf(val);
        if (t < 512) {
            int bp = t >> 7, bc = t & 127;
            float b = 0.0f;
            if (bp == 0) b = brx[bc] + brh[bc];
            else if (bp == 1) b = bux[bc] + buh[bc];
            else if (bp == 2) b = bcx[bc];
            else b = bch[bc];
            bias[t] = b;
        }
    }
}

// ------------- 2a. block-level scan (coalesced) -------------
__global__ __launch_bounds__(1024) void scanA_kernel(const int* __restrict__ counts,
                                                     int* __restrict__ pre,
                                                     int* __restrict__ partials, int N) {
    __shared__ int buf[1024];
    int tid = threadIdx.x;
    int t = blockIdx.x * 1024 + tid;
    int v = (t < N) ? counts[t] : 0;
    buf[tid] = v;
    __syncthreads();
    for (int off = 1; off < 1024; off <<= 1) {
        int o = (tid >= off) ? buf[tid - off] : 0;
        __syncthreads();
        buf[tid] += o;
        __syncthreads();
    }
    if (t < N) pre[t] = buf[tid] - v;
    if (tid == 1023) partials[blockIdx.x] = buf[1023];
}

// ------------- 2b. scan the block totals (1 block) -------------
__global__ __launch_bounds__(1024) void scanB_kernel(int* __restrict__ partials, int NB) {
    __shared__ int buf[1024];
    int tid = threadIdx.x;
    int v = (tid < NB) ? partials[tid] : 0;
    buf[tid] = v;
    __syncthreads();
    for (int off = 1; off < 1024; off <<= 1) {
        int o = (tid >= off) ? buf[tid - off] : 0;
        __syncthreads();
        buf[tid] += o;
        __syncthreads();
    }
    if (tid < NB) partials[tid] = buf[tid] - v;
}

// ------------- 2c. combine + norm (coalesced) -------------
__global__ void scanC_kernel(const int* __restrict__ counts, const int* __restrict__ pre,
                             const int* __restrict__ partials, int* __restrict__ row_ptr,
                             int* __restrict__ cursor, float* __restrict__ norm, int N, int E) {
    int i = blockIdx.x * blockDim.x + threadIdx.x;
    if (i < N) {
        int r = pre[i] + partials[i >> 10];
        row_ptr[i] = r;
        cursor[i] = r;
        int c = counts[i];
        norm[i] = rsqrtf((float)(c > 1 ? c : 1));
    }
    if (i == 0) row_ptr[N] = E;
}

// ------------- 2d. fp8 pack: xf8[n] = concat(x,hx)[n] * norm[n] -------------
// thread t: node n = t>>6, u32 lane l = t&63 -> concat-features [4l, 4l+4)
__global__ void f8conv_kernel(const u32* __restrict__ zin, const float* __restrict__ norm,
                              u32* __restrict__ xf8, int N) {
    int t = blockIdx.x * blockDim.x + threadIdx.x;
    if (t >= N * 64) return;
    int n = t >> 6, l = t & 63;
    u32 w0 = zin[(size_t)n * 256 + l * 2];
    u32 w1 = zin[(size_t)n * 256 + l * 2 + 1];
    float ns = norm[n];
    float f0 = bflo(w0) * ns, f1 = bfhi(w0) * ns;
    float f2 = bflo(w1) * ns, f3 = bfhi(w1) * ns;
    u32 out = 0;
    out = (u32)__builtin_amdgcn_cvt_pk_fp8_f32(f0, f1, (int)out, false);
    out = (u32)__builtin_amdgcn_cvt_pk_fp8_f32(f2, f3, (int)out, true);
    xf8[t] = out;
}

// ------------- 3. CSR fill, dst-range binned for XCD-local writes -------------
__global__ __launch_bounds__(256) void fill_kernel(const int* __restrict__ src,
                                                   const int* __restrict__ dst, int E,
                                                   int* __restrict__ cursor,
                                                   int* __restrict__ esrc,
                                                   int nodesPerRange, int edgesPerChunk) {
    int range = blockIdx.x & 7;
    int chunk = blockIdx.x >> 3;
    int lo = range * nodesPerRange;
    int beg = chunk * edgesPerChunk;
    int end = beg + edgesPerChunk;
    if (end > E) end = E;
    for (int i = beg + (int)threadIdx.x * 4; i < end; i += 256 * 4) {
        if (i + 4 <= end) {
            int4 s4 = *(const int4*)(src + i);
            int4 d4 = *(const int4*)(dst + i);
#pragma unroll
            for (int j = 0; j < 4; ++j) {
                int d = (j == 0) ? d4.x : (j == 1) ? d4.y : (j == 2) ? d4.z : d4.w;
                int s = (j == 0) ? s4.x : (j == 1) ? s4.y : (j == 2) ? s4.z : s4.w;
                if ((unsigned)(d - lo) < (unsigned)nodesPerRange) {
                    int slot = atomicAdd(&cursor[d], 1);
                    esrc[slot] = s;
                }
            }
        } else {
            for (int j = i; j < end; ++j) {
                int d = dst[j];
                if ((unsigned)(d - lo) < (unsigned)nodesPerRange) {
                    int slot = atomicAdd(&cursor[d], 1);
                    esrc[slot] = src[j];
                }
            }
        }
    }
}

// ------------- 4. wave-per-node fp8 gather-aggregate, 8 edges/iter -------------
// Quarter-wave (16 lanes x 16 B) covers one node's 256 B fp8 row (prescaled by
// norm[src]); each quarter runs 2 independent gathers per iteration.
__global__ __launch_bounds__(256) void agg_kernel(const int* __restrict__ row_ptr,
                                                  const int* __restrict__ esrc,
                                                  const float* __restrict__ norm,
                                                  const u32* __restrict__ xf8,
                                                  u32* __restrict__ zin, int N) {
    int node = blockIdx.x * 4 + (threadIdx.x >> 6);
    int lane = threadIdx.x & 63;
    if (node >= N) return;
    int q = lane >> 4;     // quarter 0..3 (edge slot)
    int li = lane & 15;    // 16 B slot within the 256 B fp8 row
    int beg = row_ptr[node], end = row_ptr[node + 1];
    const uint4* z4 = (const uint4*)xf8;  // 16 uint4 per node row
    f32x2 acc[8];
#pragma unroll
    for (int i = 0; i < 8; ++i) acc[i] = (f32x2){0.f, 0.f};

    int nE = end - beg;
    int mainEnd = beg + (nE & ~7);
    int e = beg;
    if (e < mainEnd) {
        int sA = esrc[e + q];
        int sB = esrc[e + q + 4];
        for (;;) {
            uint4 vA = z4[(size_t)sA * 16 + li];
            uint4 vB = z4[(size_t)sB * 16 + li];
            e += 8;
            bool more = e < mainEnd;
            int tA = 0, tB = 0;
            if (more) {
                tA = esrc[e + q];
                tB = esrc[e + q + 4];
            }
#pragma unroll
            for (int i = 0; i < 4; ++i) {
                u32 w = (i == 0) ? vA.x : (i == 1) ? vA.y : (i == 2) ? vA.z : vA.w;
                acc[2 * i] += (f32x2)__builtin_amdgcn_cvt_pk_f32_fp8((int)w, false);
                acc[2 * i + 1] += (f32x2)__builtin_amdgcn_cvt_pk_f32_fp8((int)w, true);
            }
#pragma unroll
            for (int i = 0; i < 4; ++i) {
                u32 w = (i == 0) ? vB.x : (i == 1) ? vB.y : (i == 2) ? vB.z : vB.w;
                acc[2 * i] += (f32x2)__builtin_amdgcn_cvt_pk_f32_fp8((int)w, false);
                acc[2 * i + 1] += (f32x2)__builtin_amdgcn_cvt_pk_f32_fp8((int)w, true);
            }
            if (!more) break;
            sA = tA;
            sB = tB;
        }
    }
    // tail: edges [mainEnd, end), quarter q takes every 4th
    for (int t = mainEnd + q; t < end; t += 4) {
        int s = esrc[t];
        uint4 v = z4[(size_t)s * 16 + li];
#pragma unroll
        for (int i = 0; i < 4; ++i) {
            u32 w = (i == 0) ? v.x : (i == 1) ? v.y : (i == 2) ? v.z : v.w;
            acc[2 * i] += (f32x2)__builtin_amdgcn_cvt_pk_f32_fp8((int)w, false);
            acc[2 * i + 1] += (f32x2)__builtin_amdgcn_cvt_pk_f32_fp8((int)w, true);
        }
    }
    // reduce across quarters (lanes li, li+16, li+32, li+48 hold same features)
#pragma unroll
    for (int i = 0; i < 8; ++i) {
        acc[i].x += __shfl_xor(acc[i].x, 16);
        acc[i].y += __shfl_xor(acc[i].y, 16);
        acc[i].x += __shfl_xor(acc[i].x, 32);
        acc[i].y += __shfl_xor(acc[i].y, 32);
    }
    if (lane < 16) {
        float nn = -norm[node];
        uint4 o0, o1;
        o0.x = packbf(acc[0].x * nn, acc[0].y * nn);
        o0.y = packbf(acc[1].x * nn, acc[1].y * nn);
        o0.z = packbf(acc[2].x * nn, acc[2].y * nn);
        o0.w = packbf(acc[3].x * nn, acc[3].y * nn);
        o1.x = packbf(acc[4].x * nn, acc[4].y * nn);
        o1.y = packbf(acc[5].x * nn, acc[5].y * nn);
        o1.z = packbf(acc[6].x * nn, acc[6].y * nn);
        o1.w = packbf(acc[7].x * nn, acc[7].y * nn);
        // px|ph slots: u32 base = node*256 + 128 + li*8  (uint4 index node*64+32+li*2)
        uint4* dst4 = (uint4*)zin + (size_t)node * 64 + 32 + li * 2;
        dst4[0] = o0;
        dst4[1] = o1;
    }
}

// ------------- 5. MFMA GEMM: Z[M,512] = A[M,512] * B^T (B stored [col][k]) -------------
__global__ __launch_bounds__(256) void gemm_kernel(const u16* __restrict__ A,
                                                   const u16* __restrict__ B,
                                                   u16* __restrict__ C, int M) {
    __shared__ __align__(16) __bf16 As[128 * 32];
    __shared__ __align__(16) __bf16 Bs[128 * 32];
    int tid = threadIdx.x;
    int wave = tid >> 6, lane = tid & 63;
    int m0 = blockIdx.x * 128;
    int n0 = blockIdx.y * 128;
    int wm = wave & 1, wn = wave >> 1;
    int quad = lane >> 4, l15 = lane & 15;

    f32x4 acc[4][4];
#pragma unroll
    for (int mi = 0; mi < 4; ++mi)
#pragma unroll
        for (int ni = 0; ni < 4; ++ni) acc[mi][ni] = (f32x4){0.f, 0.f, 0.f, 0.f};

    for (int k0 = 0; k0 < 512; k0 += 32) {
        __syncthreads();
#pragma unroll
        for (int j = 0; j < 2; ++j) {
            int chunk = wave * 2 + j;
            int fl = chunk * 512 + lane * 8;
            int row = fl >> 5;
            int col = fl & 31;
            async_copy16(&As[chunk * 512], A + (size_t)(m0 + row) * 512 + k0 + col);
            async_copy16(&Bs[chunk * 512], B + (size_t)(n0 + row) * 512 + k0 + col);
        }
        __syncthreads();
        bf16x8 af[4], bfr[4];
#pragma unroll
        for (int mi = 0; mi < 4; ++mi)
            af[mi] = *(const bf16x8*)&As[(wm * 64 + mi * 16 + l15) * 32 + quad * 8];
#pragma unroll
        for (int ni = 0; ni < 4; ++ni)
            bfr[ni] = *(const bf16x8*)&Bs[(wn * 64 + ni * 16 + l15) * 32 + quad * 8];
#pragma unroll
        for (int mi = 0; mi < 4; ++mi)
#pragma unroll
            for (int ni = 0; ni < 4; ++ni)
                acc[mi][ni] = __builtin_amdgcn_mfma_f32_16x16x32_bf16(af[mi], bfr[ni],
                                                                      acc[mi][ni], 0, 0, 0);
    }
#pragma unroll
    for (int mi = 0; mi < 4; ++mi)
#pragma unroll
        for (int ni = 0; ni < 4; ++ni)
#pragma unroll
            for (int r = 0; r < 4; ++r) {
                int row = m0 + wm * 64 + mi * 16 + quad * 4 + r;
                int col = n0 + wn * 64 + ni * 16 + l15;
                C[(size_t)row * 512 + col] = f2bf(acc[mi][ni][r]);
            }
}

// ------------- 6. gate epilogue (fp32 out), 2 features/thread -------------
__global__ void epilogue_kernel(const u32* __restrict__ Z, const float* __restrict__ bias,
                                const float* __restrict__ hx, float* __restrict__ out, int N) {
    int t = blockIdx.x * blockDim.x + threadIdx.x;
    if (t >= N * 64) return;
    int n = t >> 6, l = t & 63;
    const u32* z = Z + (size_t)n * 256;
    const float2* b2 = (const float2*)bias;
    u32 wr = z[l], wu = z[64 + l], wcx = z[128 + l], wch = z[192 + l];
    float2 br = b2[l], bu = b2[64 + l], bcx = b2[128 + l], bch = b2[192 + l];
    float2 h = ((const float2*)hx)[t];
    float r0 = sigmoidf_(bflo(wr) + br.x);
    float r1 = sigmoidf_(bfhi(wr) + br.y);
    float u0 = sigmoidf_(bflo(wu) + bu.x);
    float u1 = sigmoidf_(bfhi(wu) + bu.y);
    float c0 = sigmoidf_((bflo(wcx) + bcx.x) + (bflo(wch) + bch.x) * r0);
    float c1 = sigmoidf_((bfhi(wcx) + bcx.y) + (bfhi(wch) + bch.y) * r1);
    float2 o;
    o.x = u0 * h.x + (1.0f - u0) * c0;
    o.y = u1 * h.y + (1.0f - u1) * c1;
    ((float2*)out)[t] = o;
}

extern "C" void kernel_launch(void* const* d_in, const int* in_sizes, int n_in,
                              void* d_out, int out_size, void* d_ws, size_t ws_size,
                              hipStream_t stream) {
    const int* ei = (const int*)d_in[0];
    int E = in_sizes[0] / 2;
    const float* x = (const float*)d_in[1];
    const float* hx = (const float*)d_in[2];
    int N = in_sizes[1] / F_IN;
    const float* Wrx = (const float*)d_in[3];
    const float* brx = (const float*)d_in[4];
    const float* Wrh = (const float*)d_in[5];
    const float* brh = (const float*)d_in[6];
    const float* Wux = (const float*)d_in[7];
    const float* bux = (const float*)d_in[8];
    const float* Wuh = (const float*)d_in[9];
    const float* buh = (const float*)d_in[10];
    const float* Wcx = (const float*)d_in[11];
    const float* bcx = (const float*)d_in[12];
    const float* Wch = (const float*)d_in[13];
    const float* bch = (const float*)d_in[14];

    int Mpad = ((N + 127) / 128) * 128;

    char* ws = (char*)d_ws;
    size_t off = 0;
    auto alloc = [&](size_t bytes) {
        size_t o = off;
        off = (off + bytes + 255) & ~(size_t)255;
        return o;
    };
    int* counts = (int*)(ws + alloc((size_t)N * 4));
    int* cursor = (int*)(ws + alloc((size_t)N * 4));
    int* row_ptr = (int*)(ws + alloc((size_t)(N + 1) * 4));
    float* norm = (float*)(ws + alloc((size_t)N * 4));
    int* pre = (int*)(ws + alloc((size_t)N * 4));
    int* partials = (int*)(ws + alloc((size_t)1024 * 4));
    int* esrc = (int*)(ws + alloc((size_t)E * 4));
    u16* WT = (u16*)(ws + alloc((size_t)512 * 512 * 2));
    float* bias = (float*)(ws + alloc((size_t)512 * 4));
    u32* xf8 = (u32*)(ws + alloc((size_t)N * 64 * 4));
    u16* Zin = (u16*)(ws + alloc((size_t)Mpad * 512 * 2));
    u16* Zout = (u16*)(ws + alloc((size_t)Mpad * 512 * 2));
    (void)ws_size;

    int BC = (E + 255) / 256;
    int BV = (N * 64 + 255) / 256;
    int BP = (512 * 512) / 256;
    int NB = (N + 1023) / 1024;

    hipMemsetAsync(counts, 0, (size_t)N * 4, stream);
    setup_kernel<<<BC + BV + BP, 256, 0, stream>>>(ei + E, E, counts, x, hx, (u32*)Zin, N,
                                                   Wrx, Wrh, Wux, Wuh, Wcx, Wch,
                                                   brx, brh, bux, buh, bcx, bch,
                                                   WT, bias, BC, BV);
    scanA_kernel<<<NB, 1024, 0, stream>>>(counts, pre, partials, N);
    scanB_kernel<<<1, 1024, 0, stream>>>(partials, NB);
    scanC_kernel<<<(N + 255) / 256, 256, 0, stream>>>(counts, pre, partials, row_ptr,
                                                      cursor, norm, N, E);
    f8conv_kernel<<<(N * 64 + 255) / 256, 256, 0, stream>>>((const u32*)Zin, norm, xf8, N);
    const int numChunks = 128;
    int edgesPerChunk = (((E + numChunks - 1) / numChunks) + 1023) & ~1023;
    int nodesPerRange = (N + 7) / 8;
    fill_kernel<<<numChunks * 8, 256, 0, stream>>>(ei, ei + E, E, cursor, esrc,
                                                   nodesPerRange, edgesPerChunk);
    agg_kernel<<<(N + 3) / 4, 256, 0, stream>>>(row_ptr, esrc, norm, xf8, (u32*)Zin, N);
    dim3 ggrid(Mpad / 128, 4);
    gemm_kernel<<<ggrid, 256, 0, stream>>>(Zin, WT, Zout, Mpad);
    epilogue_kernel<<<((size_t)N * 64 + 255) / 256, 256, 0, stream>>>((const u32*)Zout, bias, hx,
                                                                      (float*)d_out, N);
}

// Round 7
// 366.198 us; speedup vs baseline: 1.8842x; 1.0852x over previous
//
#include <hip/hip_runtime.h>
#include <hip/hip_bf16.h>

// GConvGRU (ChebConv K=2), fp32 in/out; bf16 MFMA GEMM; fp8 gather path.
// Zin row K-layout: [x | hx | px | ph] (512 bf16 = 1 KB/node).
// xf8[n]: 256 fp8 bytes = concat(x[n],hx[n]) * norm[n]  (prescaled).
// Pipeline: memset -> count(binned LDS hist) -> scanA/B/C -> convert(bf16+fp8)
//           -> prep -> fill(binned) -> agg(fp8) -> gemm -> epilogue

typedef unsigned short u16;
typedef unsigned int u32;
typedef __attribute__((ext_vector_type(8))) __bf16 bf16x8;
typedef __attribute__((ext_vector_type(4))) float f32x4;
typedef __attribute__((ext_vector_type(2))) float f32x2;

#define F_IN 128
#define HID 128

__device__ __forceinline__ u16 f2bf(float f) {
    u32 u;
    __builtin_memcpy(&u, &f, 4);
    u = (u + 0x7fffu + ((u >> 16) & 1u)) >> 16;
    return (u16)u;
}
__device__ __forceinline__ float bflo(u32 w) {
    u32 u = w << 16;
    float f;
    __builtin_memcpy(&f, &u, 4);
    return f;
}
__device__ __forceinline__ float bfhi(u32 w) {
    u32 u = w & 0xffff0000u;
    float f;
    __builtin_memcpy(&f, &u, 4);
    return f;
}
__device__ __forceinline__ u32 packbf(float a, float b) {
    return ((u32)f2bf(b) << 16) | (u32)f2bf(a);
}
__device__ __forceinline__ float sigmoidf_(float x) {
    return 1.0f / (1.0f + __expf(-x));
}

__device__ __forceinline__ void async_copy16(void* lds, const void* gptr) {
    __builtin_amdgcn_global_load_lds(
        (__attribute__((address_space(1))) void*)gptr,
        (__attribute__((address_space(3))) void*)lds,
        16, 0, 0);
}

// ------------- 1. degree count: binned LDS histogram, XCD-local merge -------------
// grid = chunks*8; range = blockIdx&7 (round-robin block->XCD heuristic).
__global__ __launch_bounds__(256) void count_kernel(const int* __restrict__ dst, int E,
                                                    int* __restrict__ counts,
                                                    int nodesPerRange, int edgesPerChunk,
                                                    int N) {
    extern __shared__ int hist[];
    int range = blockIdx.x & 7;
    int chunk = blockIdx.x >> 3;
    int lo = range * nodesPerRange;
    int hiN = N - lo;
    int npr = nodesPerRange < hiN ? nodesPerRange : hiN;
    for (int j = threadIdx.x; j < npr; j += 256) hist[j] = 0;
    __syncthreads();
    int beg = chunk * edgesPerChunk;
    int end = beg + edgesPerChunk;
    if (end > E) end = E;
    for (int i = beg + (int)threadIdx.x * 4; i < end; i += 256 * 4) {
        if (i + 4 <= end) {
            int4 d4 = *(const int4*)(dst + i);
#pragma unroll
            for (int j = 0; j < 4; ++j) {
                int d = (j == 0) ? d4.x : (j == 1) ? d4.y : (j == 2) ? d4.z : d4.w;
                unsigned r = (unsigned)(d - lo);
                if (r < (unsigned)npr) atomicAdd(&hist[r], 1);
            }
        } else {
            for (int j = i; j < end; ++j) {
                unsigned r = (unsigned)(dst[j] - lo);
                if (r < (unsigned)npr) atomicAdd(&hist[r], 1);
            }
        }
    }
    __syncthreads();
    for (int j = threadIdx.x; j < npr; j += 256) {
        int v = hist[j];
        if (v) atomicAdd(&counts[lo + j], v);
    }
}

// ------------- 2a. block-level scan (coalesced) -------------
__global__ __launch_bounds__(1024) void scanA_kernel(const int* __restrict__ counts,
                                                     int* __restrict__ pre,
                                                     int* __restrict__ partials, int N) {
    __shared__ int buf[1024];
    int tid = threadIdx.x;
    int t = blockIdx.x * 1024 + tid;
    int v = (t < N) ? counts[t] : 0;
    buf[tid] = v;
    __syncthreads();
    for (int off = 1; off < 1024; off <<= 1) {
        int o = (tid >= off) ? buf[tid - off] : 0;
        __syncthreads();
        buf[tid] += o;
        __syncthreads();
    }
    if (t < N) pre[t] = buf[tid] - v;
    if (tid == 1023) partials[blockIdx.x] = buf[1023];
}

// ------------- 2b. scan the block totals (1 block) -------------
__global__ __launch_bounds__(1024) void scanB_kernel(int* __restrict__ partials, int NB) {
    __shared__ int buf[1024];
    int tid = threadIdx.x;
    int v = (tid < NB) ? partials[tid] : 0;
    buf[tid] = v;
    __syncthreads();
    for (int off = 1; off < 1024; off <<= 1) {
        int o = (tid >= off) ? buf[tid - off] : 0;
        __syncthreads();
        buf[tid] += o;
        __syncthreads();
    }
    if (tid < NB) partials[tid] = buf[tid] - v;
}

// ------------- 2c. combine + norm (coalesced) -------------
__global__ void scanC_kernel(const int* __restrict__ counts, const int* __restrict__ pre,
                             const int* __restrict__ partials, int* __restrict__ row_ptr,
                             int* __restrict__ cursor, float* __restrict__ norm, int N, int E) {
    int i = blockIdx.x * blockDim.x + threadIdx.x;
    if (i < N) {
        int r = pre[i] + partials[i >> 10];
        row_ptr[i] = r;
        cursor[i] = r;
        int c = counts[i];
        norm[i] = rsqrtf((float)(c > 1 ? c : 1));
    }
    if (i == 0) row_ptr[N] = E;
}

// ------------- 3. convert: x,hx -> Zin bf16 slots + prescaled fp8 rows -------------
// thread t: node n = t>>6, u32 slot c4 = t&63 of the concat [x|hx] (4 features)
__global__ void convert_kernel(const float* __restrict__ x, const float* __restrict__ hx,
                               const float* __restrict__ norm,
                               u32* __restrict__ zin, u32* __restrict__ xf8, int N) {
    int t = blockIdx.x * blockDim.x + threadIdx.x;
    if (t >= N * 64) return;
    int n = t >> 6, c4 = t & 63;
    float4 v;
    int zbase;
    if (c4 < 32) {
        v = ((const float4*)x)[n * 32 + c4];
        zbase = n * 256 + 2 * c4;
    } else {
        v = ((const float4*)hx)[n * 32 + (c4 - 32)];
        zbase = n * 256 + 64 + 2 * (c4 - 32);
    }
    zin[zbase] = packbf(v.x, v.y);
    zin[zbase + 1] = packbf(v.z, v.w);
    float ns = norm[n];
    u32 o = 0;
    o = (u32)__builtin_amdgcn_cvt_pk_fp8_f32(v.x * ns, v.y * ns, (int)o, false);
    o = (u32)__builtin_amdgcn_cvt_pk_fp8_f32(v.z * ns, v.w * ns, (int)o, true);
    xf8[t] = o;
}

// ------------- 4. weight prepack (fp32 -> bf16) + bias pack -------------
__global__ void prep_kernel(const float* __restrict__ Wrx, const float* __restrict__ Wrh,
                            const float* __restrict__ Wux, const float* __restrict__ Wuh,
                            const float* __restrict__ Wcx, const float* __restrict__ Wch,
                            const float* __restrict__ brx, const float* __restrict__ brh,
                            const float* __restrict__ bux, const float* __restrict__ buh,
                            const float* __restrict__ bcx, const float* __restrict__ bch,
                            u16* __restrict__ WT, float* __restrict__ bias) {
    int t = blockIdx.x * blockDim.x + threadIdx.x;  // [0, 512*512)
    int c = t >> 9, k = t & 511;
    int part = c >> 7, c0 = c & 127;
    int kpart = k >> 7;
    int kf = k & 127;
    int t01 = (kpart & 2) ? 1 : 0;     // x,hx -> T0 weight; px,ph -> T1 weight
    bool isX = !(kpart & 1);           // kpart 0,2 = x-side; 1,3 = h-side
    int wi = t01 * (128 * 128) + kf * 128 + c0;
    float val = 0.0f;
    if (part == 0) val = isX ? Wrx[wi] : Wrh[wi];
    else if (part == 1) val = isX ? Wux[wi] : Wuh[wi];
    else if (part == 2) { if (isX) val = Wcx[wi]; }
    else { if (!isX) val = Wch[wi]; }
    WT[c * 512 + k] = f2bf(val);
    if (t < 512) {
        int bp = t >> 7, bc = t & 127;
        float b = 0.0f;
        if (bp == 0) b = brx[bc] + brh[bc];
        else if (bp == 1) b = bux[bc] + buh[bc];
        else if (bp == 2) b = bcx[bc];
        else b = bch[bc];
        bias[t] = b;
    }
}

// ------------- 5. CSR fill, dst-range binned for XCD-local writes -------------
__global__ __launch_bounds__(256) void fill_kernel(const int* __restrict__ src,
                                                   const int* __restrict__ dst, int E,
                                                   int* __restrict__ cursor,
                                                   int* __restrict__ esrc,
                                                   int nodesPerRange, int edgesPerChunk) {
    int range = blockIdx.x & 7;
    int chunk = blockIdx.x >> 3;
    int lo = range * nodesPerRange;
    int beg = chunk * edgesPerChunk;
    int end = beg + edgesPerChunk;
    if (end > E) end = E;
    for (int i = beg + (int)threadIdx.x * 4; i < end; i += 256 * 4) {
        if (i + 4 <= end) {
            int4 s4 = *(const int4*)(src + i);
            int4 d4 = *(const int4*)(dst + i);
#pragma unroll
            for (int j = 0; j < 4; ++j) {
                int d = (j == 0) ? d4.x : (j == 1) ? d4.y : (j == 2) ? d4.z : d4.w;
                int s = (j == 0) ? s4.x : (j == 1) ? s4.y : (j == 2) ? s4.z : s4.w;
                if ((unsigned)(d - lo) < (unsigned)nodesPerRange) {
                    int slot = atomicAdd(&cursor[d], 1);
                    esrc[slot] = s;
                }
            }
        } else {
            for (int j = i; j < end; ++j) {
                int d = dst[j];
                if ((unsigned)(d - lo) < (unsigned)nodesPerRange) {
                    int slot = atomicAdd(&cursor[d], 1);
                    esrc[slot] = src[j];
                }
            }
        }
    }
}

// ------------- 6. wave-per-node fp8 gather-aggregate, 8 edges/iter -------------
__global__ __launch_bounds__(256) void agg_kernel(const int* __restrict__ row_ptr,
                                                  const int* __restrict__ esrc,
                                                  const float* __restrict__ norm,
                                                  const u32* __restrict__ xf8,
                                                  u32* __restrict__ zin, int N) {
    int node = blockIdx.x * 4 + (threadIdx.x >> 6);
    int lane = threadIdx.x & 63;
    if (node >= N) return;
    int q = lane >> 4;     // quarter 0..3 (edge slot)
    int li = lane & 15;    // 16 B slot within the 256 B fp8 row
    int beg = row_ptr[node], end = row_ptr[node + 1];
    const uint4* z4 = (const uint4*)xf8;  // 16 uint4 per node row
    f32x2 acc[8];
#pragma unroll
    for (int i = 0; i < 8; ++i) acc[i] = (f32x2){0.f, 0.f};

    int nE = end - beg;
    int mainEnd = beg + (nE & ~7);
    int e = beg;
    if (e < mainEnd) {
        int sA = esrc[e + q];
        int sB = esrc[e + q + 4];
        for (;;) {
            uint4 vA = z4[(size_t)sA * 16 + li];
            uint4 vB = z4[(size_t)sB * 16 + li];
            e += 8;
            bool more = e < mainEnd;
            int tA = 0, tB = 0;
            if (more) {
                tA = esrc[e + q];
                tB = esrc[e + q + 4];
            }
#pragma unroll
            for (int i = 0; i < 4; ++i) {
                u32 w = (i == 0) ? vA.x : (i == 1) ? vA.y : (i == 2) ? vA.z : vA.w;
                acc[2 * i] += (f32x2)__builtin_amdgcn_cvt_pk_f32_fp8((int)w, false);
                acc[2 * i + 1] += (f32x2)__builtin_amdgcn_cvt_pk_f32_fp8((int)w, true);
            }
#pragma unroll
            for (int i = 0; i < 4; ++i) {
                u32 w = (i == 0) ? vB.x : (i == 1) ? vB.y : (i == 2) ? vB.z : vB.w;
                acc[2 * i] += (f32x2)__builtin_amdgcn_cvt_pk_f32_fp8((int)w, false);
                acc[2 * i + 1] += (f32x2)__builtin_amdgcn_cvt_pk_f32_fp8((int)w, true);
            }
            if (!more) break;
            sA = tA;
            sB = tB;
        }
    }
    for (int t = mainEnd + q; t < end; t += 4) {
        int s = esrc[t];
        uint4 v = z4[(size_t)s * 16 + li];
#pragma unroll
        for (int i = 0; i < 4; ++i) {
            u32 w = (i == 0) ? v.x : (i == 1) ? v.y : (i == 2) ? v.z : v.w;
            acc[2 * i] += (f32x2)__builtin_amdgcn_cvt_pk_f32_fp8((int)w, false);
            acc[2 * i + 1] += (f32x2)__builtin_amdgcn_cvt_pk_f32_fp8((int)w, true);
        }
    }
#pragma unroll
    for (int i = 0; i < 8; ++i) {
        acc[i].x += __shfl_xor(acc[i].x, 16);
        acc[i].y += __shfl_xor(acc[i].y, 16);
        acc[i].x += __shfl_xor(acc[i].x, 32);
        acc[i].y += __shfl_xor(acc[i].y, 32);
    }
    if (lane < 16) {
        float nn = -norm[node];
        uint4 o0, o1;
        o0.x = packbf(acc[0].x * nn, acc[0].y * nn);
        o0.y = packbf(acc[1].x * nn, acc[1].y * nn);
        o0.z = packbf(acc[2].x * nn, acc[2].y * nn);
        o0.w = packbf(acc[3].x * nn, acc[3].y * nn);
        o1.x = packbf(acc[4].x * nn, acc[4].y * nn);
        o1.y = packbf(acc[5].x * nn, acc[5].y * nn);
        o1.z = packbf(acc[6].x * nn, acc[6].y * nn);
        o1.w = packbf(acc[7].x * nn, acc[7].y * nn);
        uint4* dst4 = (uint4*)zin + (size_t)node * 64 + 32 + li * 2;
        dst4[0] = o0;
        dst4[1] = o1;
    }
}

// ------------- 7. MFMA GEMM: Z[M,512] = A[M,512] * B^T (B stored [col][k]) -------------
__global__ __launch_bounds__(256) void gemm_kernel(const u16* __restrict__ A,
                                                   const u16* __restrict__ B,
                                                   u16* __restrict__ C, int M) {
    __shared__ __align__(16) __bf16 As[128 * 32];
    __shared__ __align__(16) __bf16 Bs[128 * 32];
    int tid = threadIdx.x;
    int wave = tid >> 6, lane = tid & 63;
    int m0 = blockIdx.x * 128;
    int n0 = blockIdx.y * 128;
    int wm = wave & 1, wn = wave >> 1;
    int quad = lane >> 4, l15 = lane & 15;

    f32x4 acc[4][4];
#pragma unroll
    for (int mi = 0; mi < 4; ++mi)
#pragma unroll
        for (int ni = 0; ni < 4; ++ni) acc[mi][ni] = (f32x4){0.f, 0.f, 0.f, 0.f};

    for (int k0 = 0; k0 < 512; k0 += 32) {
        __syncthreads();
#pragma unroll
        for (int j = 0; j < 2; ++j) {
            int chunk = wave * 2 + j;
            int fl = chunk * 512 + lane * 8;
            int row = fl >> 5;
            int col = fl & 31;
            async_copy16(&As[chunk * 512], A + (size_t)(m0 + row) * 512 + k0 + col);
            async_copy16(&Bs[chunk * 512], B + (size_t)(n0 + row) * 512 + k0 + col);
        }
        __syncthreads();
        bf16x8 af[4], bfr[4];
#pragma unroll
        for (int mi = 0; mi < 4; ++mi)
            af[mi] = *(const bf16x8*)&As[(wm * 64 + mi * 16 + l15) * 32 + quad * 8];
#pragma unroll
        for (int ni = 0; ni < 4; ++ni)
            bfr[ni] = *(const bf16x8*)&Bs[(wn * 64 + ni * 16 + l15) * 32 + quad * 8];
#pragma unroll
        for (int mi = 0; mi < 4; ++mi)
#pragma unroll
            for (int ni = 0; ni < 4; ++ni)
                acc[mi][ni] = __builtin_amdgcn_mfma_f32_16x16x32_bf16(af[mi], bfr[ni],
                                                                      acc[mi][ni], 0, 0, 0);
    }
#pragma unroll
    for (int mi = 0; mi < 4; ++mi)
#pragma unroll
        for (int ni = 0; ni < 4; ++ni)
#pragma unroll
            for (int r = 0; r < 4; ++r) {
                int row = m0 + wm * 64 + mi * 16 + quad * 4 + r;
                int col = n0 + wn * 64 + ni * 16 + l15;
                C[(size_t)row * 512 + col] = f2bf(acc[mi][ni][r]);
            }
}

// ------------- 8. gate epilogue (fp32 out), 2 features/thread -------------
__global__ void epilogue_kernel(const u32* __restrict__ Z, const float* __restrict__ bias,
                                const float* __restrict__ hx, float* __restrict__ out, int N) {
    int t = blockIdx.x * blockDim.x + threadIdx.x;
    if (t >= N * 64) return;
    int n = t >> 6, l = t & 63;
    const u32* z = Z + (size_t)n * 256;
    const float2* b2 = (const float2*)bias;
    u32 wr = z[l], wu = z[64 + l], wcx = z[128 + l], wch = z[192 + l];
    float2 br = b2[l], bu = b2[64 + l], bcx = b2[128 + l], bch = b2[192 + l];
    float2 h = ((const float2*)hx)[t];
    float r0 = sigmoidf_(bflo(wr) + br.x);
    float r1 = sigmoidf_(bfhi(wr) + br.y);
    float u0 = sigmoidf_(bflo(wu) + bu.x);
    float u1 = sigmoidf_(bfhi(wu) + bu.y);
    float c0 = sigmoidf_((bflo(wcx) + bcx.x) + (bflo(wch) + bch.x) * r0);
    float c1 = sigmoidf_((bfhi(wcx) + bcx.y) + (bfhi(wch) + bch.y) * r1);
    float2 o;
    o.x = u0 * h.x + (1.0f - u0) * c0;
    o.y = u1 * h.y + (1.0f - u1) * c1;
    ((float2*)out)[t] = o;
}

extern "C" void kernel_launch(void* const* d_in, const int* in_sizes, int n_in,
                              void* d_out, int out_size, void* d_ws, size_t ws_size,
                              hipStream_t stream) {
    const int* ei = (const int*)d_in[0];
    int E = in_sizes[0] / 2;
    const float* x = (const float*)d_in[1];
    const float* hx = (const float*)d_in[2];
    int N = in_sizes[1] / F_IN;
    const float* Wrx = (const float*)d_in[3];
    const float* brx = (const float*)d_in[4];
    const float* Wrh = (const float*)d_in[5];
    const float* brh = (const float*)d_in[6];
    const float* Wux = (const float*)d_in[7];
    const float* bux = (const float*)d_in[8];
    const float* Wuh = (const float*)d_in[9];
    const float* buh = (const float*)d_in[10];
    const float* Wcx = (const float*)d_in[11];
    const float* bcx = (const float*)d_in[12];
    const float* Wch = (const float*)d_in[13];
    const float* bch = (const float*)d_in[14];

    int Mpad = ((N + 127) / 128) * 128;

    char* ws = (char*)d_ws;
    size_t off = 0;
    auto alloc = [&](size_t bytes) {
        size_t o = off;
        off = (off + bytes + 255) & ~(size_t)255;
        return o;
    };
    int* counts = (int*)(ws + alloc((size_t)N * 4));
    int* cursor = (int*)(ws + alloc((size_t)N * 4));
    int* row_ptr = (int*)(ws + alloc((size_t)(N + 1) * 4));
    float* norm = (float*)(ws + alloc((size_t)N * 4));
    int* pre = (int*)(ws + alloc((size_t)N * 4));
    int* partials = (int*)(ws + alloc((size_t)1024 * 4));
    int* esrc = (int*)(ws + alloc((size_t)E * 4));
    u16* WT = (u16*)(ws + alloc((size_t)512 * 512 * 2));
    float* bias = (float*)(ws + alloc((size_t)512 * 4));
    u32* xf8 = (u32*)(ws + alloc((size_t)N * 64 * 4));
    u16* Zin = (u16*)(ws + alloc((size_t)Mpad * 512 * 2));
    u16* Zout = (u16*)(ws + alloc((size_t)Mpad * 512 * 2));
    (void)ws_size;

    int NB = (N + 1023) / 1024;
    int nodesPerRange = (N + 7) / 8;

    hipMemsetAsync(counts, 0, (size_t)N * 4, stream);
    {
        const int cChunks = 32;
        int epc = (((E + cChunks - 1) / cChunks) + 1023) & ~1023;
        count_kernel<<<cChunks * 8, 256, (size_t)nodesPerRange * 4, stream>>>(
            ei + E, E, counts, nodesPerRange, epc, N);
    }
    scanA_kernel<<<NB, 1024, 0, stream>>>(counts, pre, partials, N);
    scanB_kernel<<<1, 1024, 0, stream>>>(partials, NB);
    scanC_kernel<<<(N + 255) / 256, 256, 0, stream>>>(counts, pre, partials, row_ptr,
                                                      cursor, norm, N, E);
    convert_kernel<<<(N * 64 + 255) / 256, 256, 0, stream>>>(x, hx, norm, (u32*)Zin, xf8, N);
    prep_kernel<<<1024, 256, 0, stream>>>(Wrx, Wrh, Wux, Wuh, Wcx, Wch,
                                          brx, brh, bux, buh, bcx, bch, WT, bias);
    {
        const int fChunks = 128;
        int epc = (((E + fChunks - 1) / fChunks) + 1023) & ~1023;
        fill_kernel<<<fChunks * 8, 256, 0, stream>>>(ei, ei + E, E, cursor, esrc,
                                                     nodesPerRange, epc);
    }
    agg_kernel<<<(N + 3) / 4, 256, 0, stream>>>(row_ptr, esrc, norm, xf8, (u32*)Zin, N);
    dim3 ggrid(Mpad / 128, 4);
    gemm_kernel<<<ggrid, 256, 0, stream>>>(Zin, WT, Zout, Mpad);
    epilogue_kernel<<<((size_t)N * 64 + 255) / 256, 256, 0, stream>>>((const u32*)Zout, bias, hx,
                                                                      (float*)d_out, N);
}